// Round 1
// baseline (2163.603 us; speedup 1.0000x reference)
//
#include <hip/hip_runtime.h>
#include <math.h>

// ---------------------------------------------------------------------------
// GAT graph encoder: 2x GATConv (PyG semantics, add_self_loops=False)
// Layer1: 128 -> 4 heads x 32 (concat), +b1, elu
// Layer2: 128 -> 1 head x 128 (mean over 1 head = identity), +b2, elu
// Strategy: build CSR-by-dst each launch (ws is re-poisoned), then per layer:
//   GEMM (W in LDS) -> attention dots -> one-wave-per-dst-node aggregation
//   (segment max / exp-sum / weighted gather all in registers, no atomics).
// ---------------------------------------------------------------------------

// ---------------- CSR build ----------------

__global__ void k_count(const int* __restrict__ dst, int* __restrict__ deg, int E) {
    int e = blockIdx.x * 256 + threadIdx.x;
    if (e < E) atomicAdd(&deg[dst[e]], 1);
}

// Block handles 1024 elements (4/thread); emits per-block sum.
__global__ void k_scanA(const int* __restrict__ deg, int* __restrict__ part, int N) {
    __shared__ int sd[256];
    int t = threadIdx.x;
    int base = blockIdx.x * 1024 + t * 4;
    int s = 0;
#pragma unroll
    for (int q = 0; q < 4; q++) { int idx = base + q; if (idx < N) s += deg[idx]; }
    sd[t] = s; __syncthreads();
    for (int o = 128; o > 0; o >>= 1) { if (t < o) sd[t] += sd[t + o]; __syncthreads(); }
    if (t == 0) part[blockIdx.x] = sd[0];
}

// Exclusive scan of block sums (NB <= 1024). Also writes off[N] = E.
__global__ void k_scanB(int* __restrict__ part, int NB, int* __restrict__ offN, int E) {
    __shared__ int sd[1024];
    int t = threadIdx.x;
    int v = (t < NB) ? part[t] : 0;
    sd[t] = v; __syncthreads();
    for (int ofs = 1; ofs < 1024; ofs <<= 1) {
        int w = (t >= ofs) ? sd[t - ofs] : 0;
        __syncthreads();
        sd[t] += w;
        __syncthreads();
    }
    if (t < NB) part[t] = sd[t] - v;   // exclusive
    if (t == 0) *offN = E;
}

// Recompute local scan, add block base, write off[] and cursor[].
__global__ void k_scanC(const int* __restrict__ deg, const int* __restrict__ part,
                        int* __restrict__ off, int* __restrict__ cur, int N) {
    __shared__ int sd[256];
    int t = threadIdx.x;
    int base = blockIdx.x * 1024 + t * 4;
    int v[4]; int s = 0;
#pragma unroll
    for (int q = 0; q < 4; q++) { int idx = base + q; v[q] = (idx < N) ? deg[idx] : 0; s += v[q]; }
    sd[t] = s; __syncthreads();
    for (int ofs = 1; ofs < 256; ofs <<= 1) {
        int w = (t >= ofs) ? sd[t - ofs] : 0;
        __syncthreads();
        sd[t] += w;
        __syncthreads();
    }
    int run = sd[t] - s + part[blockIdx.x];
#pragma unroll
    for (int q = 0; q < 4; q++) {
        int idx = base + q;
        if (idx < N) { off[idx] = run; cur[idx] = run; run += v[q]; }
    }
}

__global__ void k_scatter(const int* __restrict__ src, const int* __restrict__ dst,
                          int* __restrict__ cur, int* __restrict__ esrc, int E) {
    int e = blockIdx.x * 256 + threadIdx.x;
    if (e < E) {
        int pos = atomicAdd(&cur[dst[e]], 1);
        esrc[pos] = src[e];
    }
}

// ---------------- GEMM: Y[N,128] = X[N,128] @ W[128,128] ----------------
// W staged in LDS once per block; 8 rows per tile, 4 rows per thread.

__global__ __launch_bounds__(256) void k_gemm128(
    const float* __restrict__ X, const float* __restrict__ Wg,
    float* __restrict__ Y, int N)
{
    __shared__ float Wl[128 * 128];
    __shared__ float xs[8 * 128];
    int t = threadIdx.x;
    {
        const float4* s4 = (const float4*)Wg;
        float4* d4 = (float4*)Wl;
        for (int i = t; i < 128 * 128 / 4; i += 256) d4[i] = s4[i];
    }
    __syncthreads();
    const int c = t & 127;
    const int rg = t >> 7;

    for (long long base = (long long)blockIdx.x * 8; base < N; base += (long long)gridDim.x * 8) {
        // stage 8 rows of X (256 float4s, 1 per thread)
        {
            int row = t >> 5, col4 = t & 31;
            long long gr = base + row;
            float4 v = make_float4(0.f, 0.f, 0.f, 0.f);
            if (gr < N) v = ((const float4*)(X + gr * 128))[col4];
            ((float4*)xs)[t] = v;
        }
        __syncthreads();

        float a0 = 0.f, a1 = 0.f, a2 = 0.f, a3 = 0.f;
        const float* xr = xs + rg * 512;
#pragma unroll
        for (int k = 0; k < 128; k += 4) {
            float4 x0 = *(const float4*)(xr + k);
            float4 x1 = *(const float4*)(xr + 128 + k);
            float4 x2 = *(const float4*)(xr + 256 + k);
            float4 x3 = *(const float4*)(xr + 384 + k);
            float w0 = Wl[(k + 0) * 128 + c];
            float w1 = Wl[(k + 1) * 128 + c];
            float w2 = Wl[(k + 2) * 128 + c];
            float w3 = Wl[(k + 3) * 128 + c];
            a0 = fmaf(x0.w, w3, fmaf(x0.z, w2, fmaf(x0.y, w1, fmaf(x0.x, w0, a0))));
            a1 = fmaf(x1.w, w3, fmaf(x1.z, w2, fmaf(x1.y, w1, fmaf(x1.x, w0, a1))));
            a2 = fmaf(x2.w, w3, fmaf(x2.z, w2, fmaf(x2.y, w1, fmaf(x2.x, w0, a2))));
            a3 = fmaf(x3.w, w3, fmaf(x3.z, w2, fmaf(x3.y, w1, fmaf(x3.x, w0, a3))));
        }
        long long r = base + rg * 4;
        if (r + 0 < N) Y[(r + 0) * 128 + c] = a0;
        if (r + 1 < N) Y[(r + 1) * 128 + c] = a1;
        if (r + 2 < N) Y[(r + 2) * 128 + c] = a2;
        if (r + 3 < N) Y[(r + 3) * 128 + c] = a3;
        __syncthreads();
    }
}

// ---------------- attention dots: a_src[n,h] = sum_c h[n,c]*att_s[c] ----------------
// H=4: per-head groups of 32 channels; H=1: all 128 channels.

template <int H>
__global__ __launch_bounds__(256) void k_attdot(
    const float* __restrict__ Hm, const float* __restrict__ att_s,
    const float* __restrict__ att_d, float* __restrict__ as_, float* __restrict__ ad_, int N)
{
    __shared__ float ps[2][2][2];  // [row-in-block][wave-half][src/dst]
    int t = threadIdx.x;
    int r = t >> 7;
    int c = t & 127;
    long long row = (long long)blockIdx.x * 2 + r;
    float vs = 0.f, vd = 0.f;
    if (row < N) {
        float v = Hm[row * 128 + c];
        vs = v * att_s[c];
        vd = v * att_d[c];
        if (H == 4) {
#pragma unroll
            for (int m = 16; m >= 1; m >>= 1) {
                vs += __shfl_xor(vs, m, 64);
                vd += __shfl_xor(vd, m, 64);
            }
            if ((c & 31) == 0) {
                as_[row * 4 + (c >> 5)] = vs;
                ad_[row * 4 + (c >> 5)] = vd;
            }
        } else {
#pragma unroll
            for (int m = 32; m >= 1; m >>= 1) {
                vs += __shfl_xor(vs, m, 64);
                vd += __shfl_xor(vd, m, 64);
            }
            if ((c & 63) == 0) { ps[r][c >> 6][0] = vs; ps[r][c >> 6][1] = vd; }
        }
    }
    if (H == 1) {
        __syncthreads();
        if (row < N && c == 0) {
            as_[row] = ps[r][0][0] + ps[r][1][0];
            ad_[row] = ps[r][0][1] + ps[r][1][1];
        }
    }
}

// ---------------- aggregation: one wave per dst node ----------------

template <int H>
__global__ __launch_bounds__(256) void k_agg(
    const float* __restrict__ feat,   // [N,128] source features
    const float* __restrict__ asrc,   // [N,H]
    const float* __restrict__ adst,   // [N,H]
    const int*   __restrict__ off,    // [N+1]
    const int*   __restrict__ esrc,   // [E] src node per CSR slot
    const float* __restrict__ bias,   // [128]
    float*       __restrict__ out,    // [N,128]
    int N)
{
    int lane = threadIdx.x & 63;
    int node = (blockIdx.x * 256 + threadIdx.x) >> 6;
    if (node >= N) return;
    int beg = off[node], end = off[node + 1];
    int deg = end - beg;

    float adst_i[H];
#pragma unroll
    for (int h = 0; h < H; h++) adst_i[h] = adst[(size_t)node * H + h];

    // stash first chunk (<=64 edges): src index + leaky(e)
    bool act = (lane < deg);
    int jreg = 0;
    float e0[H];
#pragma unroll
    for (int h = 0; h < H; h++) e0[h] = 0.f;
    float m[H];
#pragma unroll
    for (int h = 0; h < H; h++) m[h] = -INFINITY;

    if (act) {
        jreg = esrc[beg + lane];
        if (H == 4) {
            float4 av = *(const float4*)(asrc + (size_t)jreg * 4);
            float e;
            e = av.x + adst_i[0]; e = e > 0.f ? e : 0.2f * e; e0[0] = e; m[0] = e;
            e = av.y + adst_i[1]; e = e > 0.f ? e : 0.2f * e; e0[1] = e; m[1] = e;
            e = av.z + adst_i[2]; e = e > 0.f ? e : 0.2f * e; e0[2] = e; m[2] = e;
            e = av.w + adst_i[3]; e = e > 0.f ? e : 0.2f * e; e0[3] = e; m[3] = e;
        } else {
            float e = asrc[jreg] + adst_i[0];
            e = e > 0.f ? e : 0.2f * e;
            e0[0] = e; m[0] = e;
        }
    }
    // overflow edges (deg > 64): strided
    for (int k = beg + lane + 64; k < end; k += 64) {
        int j = esrc[k];
#pragma unroll
        for (int h = 0; h < H; h++) {
            float e = asrc[(size_t)j * H + h] + adst_i[h];
            e = e > 0.f ? e : 0.2f * e;
            m[h] = fmaxf(m[h], e);
        }
    }
#pragma unroll
    for (int x = 32; x >= 1; x >>= 1) {
#pragma unroll
        for (int h = 0; h < H; h++) m[h] = fmaxf(m[h], __shfl_xor(m[h], x, 64));
    }

    float p[H], s[H];
#pragma unroll
    for (int h = 0; h < H; h++) { p[h] = 0.f; s[h] = 0.f; }
    if (act) {
#pragma unroll
        for (int h = 0; h < H; h++) { p[h] = __expf(e0[h] - m[h]); s[h] = p[h]; }
    }
    for (int k = beg + lane + 64; k < end; k += 64) {
        int j = esrc[k];
#pragma unroll
        for (int h = 0; h < H; h++) {
            float e = asrc[(size_t)j * H + h] + adst_i[h];
            e = e > 0.f ? e : 0.2f * e;
            s[h] += __expf(e - m[h]);
        }
    }
#pragma unroll
    for (int x = 32; x >= 1; x >>= 1) {
#pragma unroll
        for (int h = 0; h < H; h++) s[h] += __shfl_xor(s[h], x, 64);
    }
    float inv[H];
#pragma unroll
    for (int h = 0; h < H; h++) inv[h] = 1.f / (s[h] + 1e-16f);

    // pass 3: sequential over edges, all lanes cooperate (2 channels/lane)
    const int c0 = lane << 1;
    const int head = (H == 4) ? (lane >> 4) : 0;
    float o0 = 0.f, o1 = 0.f;
    int lim = deg < 64 ? deg : 64;
    for (int idx = 0; idx < lim; ++idx) {
        int j = __shfl(jreg, idx, 64);
        float alpha;
        if (H == 4) {
            float v0 = __shfl(p[0], idx, 64);
            float v1 = __shfl(p[1], idx, 64);
            float v2 = __shfl(p[2], idx, 64);
            float v3 = __shfl(p[3], idx, 64);
            float va = (head == 0) ? v0 : v1;
            float vb = (head == 2) ? v2 : v3;
            alpha = ((head < 2) ? va : vb) * inv[head];
        } else {
            alpha = __shfl(p[0], idx, 64) * inv[0];
        }
        float2 hv = *(const float2*)(feat + (size_t)j * 128 + c0);
        o0 = fmaf(alpha, hv.x, o0);
        o1 = fmaf(alpha, hv.y, o1);
    }
    for (int k = beg + 64; k < end; ++k) {  // rare: deg > 64
        int j = esrc[k];
        float e = asrc[(size_t)j * H + head] + adst_i[head];
        e = e > 0.f ? e : 0.2f * e;
        float alpha = __expf(e - m[head]) * inv[head];
        float2 hv = *(const float2*)(feat + (size_t)j * 128 + c0);
        o0 = fmaf(alpha, hv.x, o0);
        o1 = fmaf(alpha, hv.y, o1);
    }

    float r0 = o0 + bias[c0];
    float r1 = o1 + bias[c0 + 1];
    r0 = r0 > 0.f ? r0 : expm1f(r0);
    r1 = r1 > 0.f ? r1 : expm1f(r1);
    *(float2*)(out + (size_t)node * 128 + c0) = make_float2(r0, r1);
}

// ---------------- launch ----------------

extern "C" void kernel_launch(void* const* d_in, const int* in_sizes, int n_in,
                              void* d_out, int out_size, void* d_ws, size_t ws_size,
                              hipStream_t stream)
{
    const float* x    = (const float*)d_in[0];
    const int*   a    = (const int*)  d_in[1];
    const float* W1   = (const float*)d_in[2];
    const float* as1w = (const float*)d_in[3];
    const float* ad1w = (const float*)d_in[4];
    const float* b1   = (const float*)d_in[5];
    const float* W2   = (const float*)d_in[6];
    const float* as2w = (const float*)d_in[7];
    const float* ad2w = (const float*)d_in[8];
    const float* b2   = (const float*)d_in[9];

    const int N = in_sizes[0] / 128;
    const int E = in_sizes[1] / 2;
    const int* srcA = a;
    const int* dstA = a + E;

    char* ws = (char*)d_ws;
    size_t o = 0;
    auto alloc = [&](size_t bytes) -> void* {
        void* p = ws + o;
        o += (bytes + 255) & ~(size_t)255;
        return p;
    };
    float* hbuf = (float*)alloc((size_t)N * 128 * 4);  // h1, then reused as h2
    float* hact = (float*)alloc((size_t)N * 128 * 4);  // elu(gat1)
    float* as1  = (float*)alloc((size_t)N * 4 * 4);
    float* ad1  = (float*)alloc((size_t)N * 4 * 4);
    float* as2  = (float*)alloc((size_t)N * 4);
    float* ad2  = (float*)alloc((size_t)N * 4);
    int*   deg  = (int*)alloc((size_t)N * 4);
    int*   off  = (int*)alloc((size_t)(N + 1) * 4);
    int*   cur  = (int*)alloc((size_t)N * 4);
    int*   part = (int*)alloc(4096 * 4);
    int*   esrc = (int*)alloc((size_t)E * 4);

    // CSR build (ws is re-poisoned every call, so rebuild each launch)
    hipMemsetAsync(deg, 0, (size_t)N * 4, stream);
    int eb = (E + 255) / 256;
    k_count<<<eb, 256, 0, stream>>>(dstA, deg, E);
    int NB = (N + 1023) / 1024;
    k_scanA<<<NB, 256, 0, stream>>>(deg, part, N);
    k_scanB<<<1, 1024, 0, stream>>>(part, NB, off + N, E);
    k_scanC<<<NB, 256, 0, stream>>>(deg, part, off, cur, N);
    k_scatter<<<eb, 256, 0, stream>>>(srcA, dstA, cur, esrc, E);

    // layer 1
    k_gemm128<<<2048, 256, 0, stream>>>(x, W1, hbuf, N);
    k_attdot<4><<<(N + 1) / 2, 256, 0, stream>>>(hbuf, as1w, ad1w, as1, ad1, N);
    k_agg<4><<<(N + 3) / 4, 256, 0, stream>>>(hbuf, as1, ad1, off, esrc, b1, hact, N);

    // layer 2
    k_gemm128<<<2048, 256, 0, stream>>>(hact, W2, hbuf, N);
    k_attdot<1><<<(N + 1) / 2, 256, 0, stream>>>(hbuf, as2w, ad2w, as2, ad2, N);
    k_agg<1><<<(N + 3) / 4, 256, 0, stream>>>(hbuf, as2, ad2, off, esrc, b2, (float*)d_out, N);
}

// Round 2
// 741.463 us; speedup vs baseline: 2.9180x; 2.9180x over previous
//
#include <hip/hip_runtime.h>
#include <math.h>

// ---------------------------------------------------------------------------
// GAT graph encoder: 2x GATConv (PyG semantics, add_self_loops=False)
// Layer1: 128 -> 4 heads x 32 (concat), +b1, elu
// Layer2: 128 -> 1 head x 128 (mean over 1 head = identity), +b2, elu
// R1 fix: GEMM rewritten with 4x4 register blocking + bounded unroll.
//   R0's full #pragma unroll blew VGPRs to the 256 cap and spilled 1.7 GB
//   to scratch per dispatch (815 us/GEMM). New: 16 acc/thread, ~<=128 VGPR.
// ---------------------------------------------------------------------------

// ---------------- CSR build ----------------

__global__ void k_count(const int* __restrict__ dst, int* __restrict__ deg, int E) {
    int e = blockIdx.x * 256 + threadIdx.x;
    if (e < E) atomicAdd(&deg[dst[e]], 1);
}

// Block handles 1024 elements (4/thread); emits per-block sum.
__global__ void k_scanA(const int* __restrict__ deg, int* __restrict__ part, int N) {
    __shared__ int sd[256];
    int t = threadIdx.x;
    int base = blockIdx.x * 1024 + t * 4;
    int s = 0;
#pragma unroll
    for (int q = 0; q < 4; q++) { int idx = base + q; if (idx < N) s += deg[idx]; }
    sd[t] = s; __syncthreads();
    for (int o = 128; o > 0; o >>= 1) { if (t < o) sd[t] += sd[t + o]; __syncthreads(); }
    if (t == 0) part[blockIdx.x] = sd[0];
}

// Exclusive scan of block sums (NB <= 1024). Also writes off[N] = E.
__global__ void k_scanB(int* __restrict__ part, int NB, int* __restrict__ offN, int E) {
    __shared__ int sd[1024];
    int t = threadIdx.x;
    int v = (t < NB) ? part[t] : 0;
    sd[t] = v; __syncthreads();
    for (int ofs = 1; ofs < 1024; ofs <<= 1) {
        int w = (t >= ofs) ? sd[t - ofs] : 0;
        __syncthreads();
        sd[t] += w;
        __syncthreads();
    }
    if (t < NB) part[t] = sd[t] - v;   // exclusive
    if (t == 0) *offN = E;
}

// Recompute local scan, add block base, write off[] and cursor[].
__global__ void k_scanC(const int* __restrict__ deg, const int* __restrict__ part,
                        int* __restrict__ off, int* __restrict__ cur, int N) {
    __shared__ int sd[256];
    int t = threadIdx.x;
    int base = blockIdx.x * 1024 + t * 4;
    int v[4]; int s = 0;
#pragma unroll
    for (int q = 0; q < 4; q++) { int idx = base + q; v[q] = (idx < N) ? deg[idx] : 0; s += v[q]; }
    sd[t] = s; __syncthreads();
    for (int ofs = 1; ofs < 256; ofs <<= 1) {
        int w = (t >= ofs) ? sd[t - ofs] : 0;
        __syncthreads();
        sd[t] += w;
        __syncthreads();
    }
    int run = sd[t] - s + part[blockIdx.x];
#pragma unroll
    for (int q = 0; q < 4; q++) {
        int idx = base + q;
        if (idx < N) { off[idx] = run; cur[idx] = run; run += v[q]; }
    }
}

__global__ void k_scatter(const int* __restrict__ src, const int* __restrict__ dst,
                          int* __restrict__ cur, int* __restrict__ esrc, int E) {
    int e = blockIdx.x * 256 + threadIdx.x;
    if (e < E) {
        int pos = atomicAdd(&cur[dst[e]], 1);
        esrc[pos] = src[e];
    }
}

// ---------------- GEMM: Y[N,128] = X[N,128] @ W[128,128] ----------------
// W (64 KB) staged in LDS once per block; 32-row tiles, each thread computes
// a 4x4 register block (rows 4*ty.., cols 4*tx..). Bounded unroll (VGPR!).

#define FMA4(A, s, Wv) \
    A.x = fmaf(s, Wv.x, A.x); A.y = fmaf(s, Wv.y, A.y); \
    A.z = fmaf(s, Wv.z, A.z); A.w = fmaf(s, Wv.w, A.w);

__global__ __launch_bounds__(256) void k_gemm128(
    const float* __restrict__ X, const float* __restrict__ Wg,
    float* __restrict__ Y, int N)
{
    __shared__ float Wl[128 * 128];
    __shared__ float xs[32 * 128];
    int t = threadIdx.x;
    for (int i = t; i < 128 * 128 / 4; i += 256) ((float4*)Wl)[i] = ((const float4*)Wg)[i];
    __syncthreads();

    const int tx = t & 31;    // col group -> cols 4*tx..4*tx+3
    const int ty = t >> 5;    // row group -> rows 4*ty..4*ty+3 of the tile
    const int c0 = tx * 4;

    for (int base = blockIdx.x * 32; base < N; base += gridDim.x * 32) {
        // stage 32 rows of X: 1024 float4s, 4 per thread
        for (int i = t; i < 1024; i += 256) {
            int row = i >> 5, col4 = i & 31;
            int gr = base + row;
            float4 v = make_float4(0.f, 0.f, 0.f, 0.f);
            if (gr < N) v = ((const float4*)(X + (size_t)gr * 128))[col4];
            ((float4*)xs)[i] = v;
        }
        __syncthreads();

        float4 a0 = make_float4(0.f, 0.f, 0.f, 0.f);
        float4 a1 = a0, a2 = a0, a3 = a0;
        const float* xr = xs + ty * 4 * 128;
#pragma unroll 2
        for (int k = 0; k < 128; k += 4) {
            float4 x0 = *(const float4*)(xr + 0 * 128 + k);
            float4 x1 = *(const float4*)(xr + 1 * 128 + k);
            float4 x2 = *(const float4*)(xr + 2 * 128 + k);
            float4 x3 = *(const float4*)(xr + 3 * 128 + k);
            float4 w0 = *(const float4*)(Wl + (k + 0) * 128 + c0);
            float4 w1 = *(const float4*)(Wl + (k + 1) * 128 + c0);
            float4 w2 = *(const float4*)(Wl + (k + 2) * 128 + c0);
            float4 w3 = *(const float4*)(Wl + (k + 3) * 128 + c0);
            FMA4(a0, x0.x, w0) FMA4(a0, x0.y, w1) FMA4(a0, x0.z, w2) FMA4(a0, x0.w, w3)
            FMA4(a1, x1.x, w0) FMA4(a1, x1.y, w1) FMA4(a1, x1.z, w2) FMA4(a1, x1.w, w3)
            FMA4(a2, x2.x, w0) FMA4(a2, x2.y, w1) FMA4(a2, x2.z, w2) FMA4(a2, x2.w, w3)
            FMA4(a3, x3.x, w0) FMA4(a3, x3.y, w1) FMA4(a3, x3.z, w2) FMA4(a3, x3.w, w3)
        }
        int r0 = base + ty * 4;
        if (r0 + 0 < N) *(float4*)(Y + (size_t)(r0 + 0) * 128 + c0) = a0;
        if (r0 + 1 < N) *(float4*)(Y + (size_t)(r0 + 1) * 128 + c0) = a1;
        if (r0 + 2 < N) *(float4*)(Y + (size_t)(r0 + 2) * 128 + c0) = a2;
        if (r0 + 3 < N) *(float4*)(Y + (size_t)(r0 + 3) * 128 + c0) = a3;
        __syncthreads();
    }
}

// ---------------- attention dots: a_src[n,h] = sum_c h[n,c]*att_s[c] ----------------
// H=4: per-head groups of 32 channels; H=1: all 128 channels.

template <int H>
__global__ __launch_bounds__(256) void k_attdot(
    const float* __restrict__ Hm, const float* __restrict__ att_s,
    const float* __restrict__ att_d, float* __restrict__ as_, float* __restrict__ ad_, int N)
{
    __shared__ float ps[2][2][2];  // [row-in-block][wave-half][src/dst]
    int t = threadIdx.x;
    int r = t >> 7;
    int c = t & 127;
    long long row = (long long)blockIdx.x * 2 + r;
    float vs = 0.f, vd = 0.f;
    if (row < N) {
        float v = Hm[row * 128 + c];
        vs = v * att_s[c];
        vd = v * att_d[c];
        if (H == 4) {
#pragma unroll
            for (int m = 16; m >= 1; m >>= 1) {
                vs += __shfl_xor(vs, m, 64);
                vd += __shfl_xor(vd, m, 64);
            }
            if ((c & 31) == 0) {
                as_[row * 4 + (c >> 5)] = vs;
                ad_[row * 4 + (c >> 5)] = vd;
            }
        } else {
#pragma unroll
            for (int m = 32; m >= 1; m >>= 1) {
                vs += __shfl_xor(vs, m, 64);
                vd += __shfl_xor(vd, m, 64);
            }
            if ((c & 63) == 0) { ps[r][c >> 6][0] = vs; ps[r][c >> 6][1] = vd; }
        }
    }
    if (H == 1) {
        __syncthreads();
        if (row < N && c == 0) {
            as_[row] = ps[r][0][0] + ps[r][1][0];
            ad_[row] = ps[r][0][1] + ps[r][1][1];
        }
    }
}

// ---------------- aggregation: one wave per dst node ----------------

template <int H>
__global__ __launch_bounds__(256) void k_agg(
    const float* __restrict__ feat,   // [N,128] source features
    const float* __restrict__ asrc,   // [N,H]
    const float* __restrict__ adst,   // [N,H]
    const int*   __restrict__ off,    // [N+1]
    const int*   __restrict__ esrc,   // [E] src node per CSR slot
    const float* __restrict__ bias,   // [128]
    float*       __restrict__ out,    // [N,128]
    int N)
{
    int lane = threadIdx.x & 63;
    int node = (blockIdx.x * 256 + threadIdx.x) >> 6;
    if (node >= N) return;
    int beg = off[node], end = off[node + 1];
    int deg = end - beg;

    float adst_i[H];
#pragma unroll
    for (int h = 0; h < H; h++) adst_i[h] = adst[(size_t)node * H + h];

    // stash first chunk (<=64 edges): src index + leaky(e)
    bool act = (lane < deg);
    int jreg = 0;
    float e0[H];
#pragma unroll
    for (int h = 0; h < H; h++) e0[h] = 0.f;
    float m[H];
#pragma unroll
    for (int h = 0; h < H; h++) m[h] = -INFINITY;

    if (act) {
        jreg = esrc[beg + lane];
        if (H == 4) {
            float4 av = *(const float4*)(asrc + (size_t)jreg * 4);
            float e;
            e = av.x + adst_i[0]; e = e > 0.f ? e : 0.2f * e; e0[0] = e; m[0] = e;
            e = av.y + adst_i[1]; e = e > 0.f ? e : 0.2f * e; e0[1] = e; m[1] = e;
            e = av.z + adst_i[2]; e = e > 0.f ? e : 0.2f * e; e0[2] = e; m[2] = e;
            e = av.w + adst_i[3]; e = e > 0.f ? e : 0.2f * e; e0[3] = e; m[3] = e;
        } else {
            float e = asrc[jreg] + adst_i[0];
            e = e > 0.f ? e : 0.2f * e;
            e0[0] = e; m[0] = e;
        }
    }
    // overflow edges (deg > 64): strided
    for (int k = beg + lane + 64; k < end; k += 64) {
        int j = esrc[k];
#pragma unroll
        for (int h = 0; h < H; h++) {
            float e = asrc[(size_t)j * H + h] + adst_i[h];
            e = e > 0.f ? e : 0.2f * e;
            m[h] = fmaxf(m[h], e);
        }
    }
#pragma unroll
    for (int x = 32; x >= 1; x >>= 1) {
#pragma unroll
        for (int h = 0; h < H; h++) m[h] = fmaxf(m[h], __shfl_xor(m[h], x, 64));
    }

    float p[H], s[H];
#pragma unroll
    for (int h = 0; h < H; h++) { p[h] = 0.f; s[h] = 0.f; }
    if (act) {
#pragma unroll
        for (int h = 0; h < H; h++) { p[h] = __expf(e0[h] - m[h]); s[h] = p[h]; }
    }
    for (int k = beg + lane + 64; k < end; k += 64) {
        int j = esrc[k];
#pragma unroll
        for (int h = 0; h < H; h++) {
            float e = asrc[(size_t)j * H + h] + adst_i[h];
            e = e > 0.f ? e : 0.2f * e;
            s[h] += __expf(e - m[h]);
        }
    }
#pragma unroll
    for (int x = 32; x >= 1; x >>= 1) {
#pragma unroll
        for (int h = 0; h < H; h++) s[h] += __shfl_xor(s[h], x, 64);
    }
    float inv[H];
#pragma unroll
    for (int h = 0; h < H; h++) inv[h] = 1.f / (s[h] + 1e-16f);

    // pass 3: sequential over edges, all lanes cooperate (2 channels/lane)
    const int c0 = lane << 1;
    const int head = (H == 4) ? (lane >> 4) : 0;
    float o0 = 0.f, o1 = 0.f;
    int lim = deg < 64 ? deg : 64;
    for (int idx = 0; idx < lim; ++idx) {
        int j = __shfl(jreg, idx, 64);
        float alpha;
        if (H == 4) {
            float v0 = __shfl(p[0], idx, 64);
            float v1 = __shfl(p[1], idx, 64);
            float v2 = __shfl(p[2], idx, 64);
            float v3 = __shfl(p[3], idx, 64);
            float va = (head == 0) ? v0 : v1;
            float vb = (head == 2) ? v2 : v3;
            alpha = ((head < 2) ? va : vb) * inv[head];
        } else {
            alpha = __shfl(p[0], idx, 64) * inv[0];
        }
        float2 hv = *(const float2*)(feat + (size_t)j * 128 + c0);
        o0 = fmaf(alpha, hv.x, o0);
        o1 = fmaf(alpha, hv.y, o1);
    }
    for (int k = beg + 64; k < end; ++k) {  // rare: deg > 64
        int j = esrc[k];
        float e = asrc[(size_t)j * H + head] + adst_i[head];
        e = e > 0.f ? e : 0.2f * e;
        float alpha = __expf(e - m[head]) * inv[head];
        float2 hv = *(const float2*)(feat + (size_t)j * 128 + c0);
        o0 = fmaf(alpha, hv.x, o0);
        o1 = fmaf(alpha, hv.y, o1);
    }

    float r0 = o0 + bias[c0];
    float r1 = o1 + bias[c0 + 1];
    r0 = r0 > 0.f ? r0 : expm1f(r0);
    r1 = r1 > 0.f ? r1 : expm1f(r1);
    *(float2*)(out + (size_t)node * 128 + c0) = make_float2(r0, r1);
}

// ---------------- launch ----------------

extern "C" void kernel_launch(void* const* d_in, const int* in_sizes, int n_in,
                              void* d_out, int out_size, void* d_ws, size_t ws_size,
                              hipStream_t stream)
{
    const float* x    = (const float*)d_in[0];
    const int*   a    = (const int*)  d_in[1];
    const float* W1   = (const float*)d_in[2];
    const float* as1w = (const float*)d_in[3];
    const float* ad1w = (const float*)d_in[4];
    const float* b1   = (const float*)d_in[5];
    const float* W2   = (const float*)d_in[6];
    const float* as2w = (const float*)d_in[7];
    const float* ad2w = (const float*)d_in[8];
    const float* b2   = (const float*)d_in[9];

    const int N = in_sizes[0] / 128;
    const int E = in_sizes[1] / 2;
    const int* srcA = a;
    const int* dstA = a + E;

    char* ws = (char*)d_ws;
    size_t o = 0;
    auto alloc = [&](size_t bytes) -> void* {
        void* p = ws + o;
        o += (bytes + 255) & ~(size_t)255;
        return p;
    };
    float* hbuf = (float*)alloc((size_t)N * 128 * 4);  // h1, then reused as h2
    float* hact = (float*)alloc((size_t)N * 128 * 4);  // elu(gat1)
    float* as1  = (float*)alloc((size_t)N * 4 * 4);
    float* ad1  = (float*)alloc((size_t)N * 4 * 4);
    float* as2  = (float*)alloc((size_t)N * 4);
    float* ad2  = (float*)alloc((size_t)N * 4);
    int*   deg  = (int*)alloc((size_t)N * 4);
    int*   off  = (int*)alloc((size_t)(N + 1) * 4);
    int*   cur  = (int*)alloc((size_t)N * 4);
    int*   part = (int*)alloc(4096 * 4);
    int*   esrc = (int*)alloc((size_t)E * 4);

    // CSR build (ws is re-poisoned every call, so rebuild each launch)
    hipMemsetAsync(deg, 0, (size_t)N * 4, stream);
    int eb = (E + 255) / 256;
    k_count<<<eb, 256, 0, stream>>>(dstA, deg, E);
    int NB = (N + 1023) / 1024;
    k_scanA<<<NB, 256, 0, stream>>>(deg, part, N);
    k_scanB<<<1, 1024, 0, stream>>>(part, NB, off + N, E);
    k_scanC<<<NB, 256, 0, stream>>>(deg, part, off, cur, N);
    k_scatter<<<eb, 256, 0, stream>>>(srcA, dstA, cur, esrc, E);

    // layer 1
    k_gemm128<<<512, 256, 0, stream>>>(x, W1, hbuf, N);
    k_attdot<4><<<(N + 1) / 2, 256, 0, stream>>>(hbuf, as1w, ad1w, as1, ad1, N);
    k_agg<4><<<(N + 3) / 4, 256, 0, stream>>>(hbuf, as1, ad1, off, esrc, b1, hact, N);

    // layer 2
    k_gemm128<<<512, 256, 0, stream>>>(hact, W2, hbuf, N);
    k_attdot<1><<<(N + 1) / 2, 256, 0, stream>>>(hbuf, as2w, ad2w, as2, ad2, N);
    k_agg<1><<<(N + 3) / 4, 256, 0, stream>>>(hbuf, as2, ad2, off, esrc, b2, (float*)d_out, N);
}

// Round 3
// 666.409 us; speedup vs baseline: 3.2467x; 1.1126x over previous
//
#include <hip/hip_runtime.h>
#include <math.h>

// ---------------------------------------------------------------------------
// GAT graph encoder: 2x GATConv (PyG semantics, add_self_loops=False)
// R2 analysis: k_agg was LDS-pipe bound (5 shfl/edge + 48 butterfly-ops/node).
// R3: (a) drop softmax max-shift (e bounded, exp safe in fp32, max cancels
//     exactly in exact math); (b) s accumulated redundantly per-lane in pass 3
//     (no reductions at all); (c) LDS staging: head-major p layout lets the
//     inner loop fetch 4 edges per uniform-address ds_read_b128 (~0.6 LDS
//     ops/edge vs ~8); (d) attdot fused into GEMM epilogue (2 kernels gone).
// ---------------------------------------------------------------------------

// ---------------- CSR build ----------------

__global__ void k_count(const int* __restrict__ dst, int* __restrict__ deg, int E) {
    int e = blockIdx.x * 256 + threadIdx.x;
    if (e < E) atomicAdd(&deg[dst[e]], 1);
}

__global__ void k_scanA(const int* __restrict__ deg, int* __restrict__ part, int N) {
    __shared__ int sd[256];
    int t = threadIdx.x;
    int base = blockIdx.x * 1024 + t * 4;
    int s = 0;
#pragma unroll
    for (int q = 0; q < 4; q++) { int idx = base + q; if (idx < N) s += deg[idx]; }
    sd[t] = s; __syncthreads();
    for (int o = 128; o > 0; o >>= 1) { if (t < o) sd[t] += sd[t + o]; __syncthreads(); }
    if (t == 0) part[blockIdx.x] = sd[0];
}

__global__ void k_scanB(int* __restrict__ part, int NB, int* __restrict__ offN, int E) {
    __shared__ int sd[1024];
    int t = threadIdx.x;
    int v = (t < NB) ? part[t] : 0;
    sd[t] = v; __syncthreads();
    for (int ofs = 1; ofs < 1024; ofs <<= 1) {
        int w = (t >= ofs) ? sd[t - ofs] : 0;
        __syncthreads();
        sd[t] += w;
        __syncthreads();
    }
    if (t < NB) part[t] = sd[t] - v;   // exclusive
    if (t == 0) *offN = E;
}

__global__ void k_scanC(const int* __restrict__ deg, const int* __restrict__ part,
                        int* __restrict__ off, int* __restrict__ cur, int N) {
    __shared__ int sd[256];
    int t = threadIdx.x;
    int base = blockIdx.x * 1024 + t * 4;
    int v[4]; int s = 0;
#pragma unroll
    for (int q = 0; q < 4; q++) { int idx = base + q; v[q] = (idx < N) ? deg[idx] : 0; s += v[q]; }
    sd[t] = s; __syncthreads();
    for (int ofs = 1; ofs < 256; ofs <<= 1) {
        int w = (t >= ofs) ? sd[t - ofs] : 0;
        __syncthreads();
        sd[t] += w;
        __syncthreads();
    }
    int run = sd[t] - s + part[blockIdx.x];
#pragma unroll
    for (int q = 0; q < 4; q++) {
        int idx = base + q;
        if (idx < N) { off[idx] = run; cur[idx] = run; run += v[q]; }
    }
}

__global__ void k_scatter(const int* __restrict__ src, const int* __restrict__ dst,
                          int* __restrict__ cur, int* __restrict__ esrc, int E) {
    int e = blockIdx.x * 256 + threadIdx.x;
    if (e < E) {
        int pos = atomicAdd(&cur[dst[e]], 1);
        esrc[pos] = src[e];
    }
}

// ---------------- GEMM + fused attention dots ----------------
// Y[N,128] = X[N,128] @ W[128,128]; a_src/a_dst computed in the epilogue.
// W in LDS; 32-row tiles; 4x4 register block per thread; bounded unroll.

#define FMA4(A, s, Wv) \
    A.x = fmaf(s, Wv.x, A.x); A.y = fmaf(s, Wv.y, A.y); \
    A.z = fmaf(s, Wv.z, A.z); A.w = fmaf(s, Wv.w, A.w);

template <int H>
__global__ __launch_bounds__(256) void k_gemm128(
    const float* __restrict__ X, const float* __restrict__ Wg,
    const float* __restrict__ att_s, const float* __restrict__ att_d,
    float* __restrict__ Y, float* __restrict__ as_, float* __restrict__ ad_, int N)
{
    __shared__ float Wl[128 * 128];
    __shared__ float xs[32 * 128];
    int t = threadIdx.x;
    for (int i = t; i < 128 * 128 / 4; i += 256) ((float4*)Wl)[i] = ((const float4*)Wg)[i];

    const int tx = t & 31;
    const int ty = t >> 5;
    const int c0 = tx * 4;
    const float4 atts = ((const float4*)att_s)[tx];
    const float4 attd = ((const float4*)att_d)[tx];
    __syncthreads();

    for (int base = blockIdx.x * 32; base < N; base += gridDim.x * 32) {
        for (int i = t; i < 1024; i += 256) {
            int row = i >> 5, col4 = i & 31;
            int gr = base + row;
            float4 v = make_float4(0.f, 0.f, 0.f, 0.f);
            if (gr < N) v = ((const float4*)(X + (size_t)gr * 128))[col4];
            ((float4*)xs)[i] = v;
        }
        __syncthreads();

        float4 a0 = make_float4(0.f, 0.f, 0.f, 0.f);
        float4 a1 = a0, a2 = a0, a3 = a0;
        const float* xr = xs + ty * 4 * 128;
#pragma unroll 2
        for (int k = 0; k < 128; k += 4) {
            float4 x0 = *(const float4*)(xr + 0 * 128 + k);
            float4 x1 = *(const float4*)(xr + 1 * 128 + k);
            float4 x2 = *(const float4*)(xr + 2 * 128 + k);
            float4 x3 = *(const float4*)(xr + 3 * 128 + k);
            float4 w0 = *(const float4*)(Wl + (k + 0) * 128 + c0);
            float4 w1 = *(const float4*)(Wl + (k + 1) * 128 + c0);
            float4 w2 = *(const float4*)(Wl + (k + 2) * 128 + c0);
            float4 w3 = *(const float4*)(Wl + (k + 3) * 128 + c0);
            FMA4(a0, x0.x, w0) FMA4(a0, x0.y, w1) FMA4(a0, x0.z, w2) FMA4(a0, x0.w, w3)
            FMA4(a1, x1.x, w0) FMA4(a1, x1.y, w1) FMA4(a1, x1.z, w2) FMA4(a1, x1.w, w3)
            FMA4(a2, x2.x, w0) FMA4(a2, x2.y, w1) FMA4(a2, x2.z, w2) FMA4(a2, x2.w, w3)
            FMA4(a3, x3.x, w0) FMA4(a3, x3.y, w1) FMA4(a3, x3.z, w2) FMA4(a3, x3.w, w3)
        }
        int r0 = base + ty * 4;
        if (r0 + 0 < N) *(float4*)(Y + (size_t)(r0 + 0) * 128 + c0) = a0;
        if (r0 + 1 < N) *(float4*)(Y + (size_t)(r0 + 1) * 128 + c0) = a1;
        if (r0 + 2 < N) *(float4*)(Y + (size_t)(r0 + 2) * 128 + c0) = a2;
        if (r0 + 3 < N) *(float4*)(Y + (size_t)(r0 + 3) * 128 + c0) = a3;

        // fused attention dots: per-row partial dot over this thread's 4 cols,
        // then shfl-reduce across tx (within-head for H=4, all 32 for H=1).
        float ps[4], pd[4];
#pragma unroll
        for (int i = 0; i < 4; i++) {
            float4 ai = (i == 0) ? a0 : (i == 1) ? a1 : (i == 2) ? a2 : a3;
            ps[i] = ai.x * atts.x + ai.y * atts.y + ai.z * atts.z + ai.w * atts.w;
            pd[i] = ai.x * attd.x + ai.y * attd.y + ai.z * attd.z + ai.w * attd.w;
        }
        const int levels = (H == 4) ? 4 : 16;   // masks 1..4 or 1..16
        for (int msk = 1; msk < levels + ((H == 4) ? 1 : 1); msk <<= 1) {
#pragma unroll
            for (int i = 0; i < 4; i++) {
                ps[i] += __shfl_xor(ps[i], msk, 64);
                pd[i] += __shfl_xor(pd[i], msk, 64);
            }
            if (msk >= levels) break;
        }
        if (H == 4) {
            if ((tx & 7) == 0) {
                int head = tx >> 3;
#pragma unroll
                for (int i = 0; i < 4; i++) {
                    if (r0 + i < N) {
                        as_[(size_t)(r0 + i) * 4 + head] = ps[i];
                        ad_[(size_t)(r0 + i) * 4 + head] = pd[i];
                    }
                }
            }
        } else {
            if (tx == 0) {
#pragma unroll
                for (int i = 0; i < 4; i++) {
                    if (r0 + i < N) { as_[r0 + i] = ps[i]; ad_[r0 + i] = pd[i]; }
                }
            }
        }
        __syncthreads();
    }
}

// ---------------- aggregation: one wave per dst node, LDS-staged chunks ----
// No softmax max-shift (exact cancel; e bounded so exp is fp32-safe).
// s accumulated redundantly by every lane during the gather loop.

template <int H>
__global__ __launch_bounds__(256) void k_agg(
    const float* __restrict__ feat,   // [N,128]
    const float* __restrict__ asrc,   // [N,H]
    const float* __restrict__ adst,   // [N,H]
    const int*   __restrict__ off,    // [N+1]
    const int*   __restrict__ esrc,   // [E]
    const float* __restrict__ bias,   // [128]
    float*       __restrict__ out,    // [N,128]
    int N)
{
    __shared__ __attribute__((aligned(16))) int   sj[4][64];
    __shared__ __attribute__((aligned(16))) float sp[4][64 * H];  // head-major

    int wave = threadIdx.x >> 6;
    int lane = threadIdx.x & 63;
    int node = (blockIdx.x * 256 + threadIdx.x) >> 6;
    if (node >= N) return;
    int beg = off[node], end = off[node + 1];

    float adst_i[H];
#pragma unroll
    for (int h = 0; h < H; h++) adst_i[h] = adst[(size_t)node * H + h];

    const int c0 = lane << 1;
    const int head = (H == 4) ? (lane >> 4) : 0;
    const float* fb = feat + c0;
    float o0 = 0.f, o1 = 0.f, ssum = 0.f;

    for (int cbeg = beg; cbeg < end; cbeg += 64) {
        int cnt = end - cbeg; if (cnt > 64) cnt = 64;
        if (lane < cnt) {
            int j = esrc[cbeg + lane];
            sj[wave][lane] = j;
            if (H == 4) {
                float4 av = *(const float4*)(asrc + (size_t)j * 4);
                float e;
                e = av.x + adst_i[0]; e = e > 0.f ? e : 0.2f * e; sp[wave][0 * 64 + lane] = __expf(e);
                e = av.y + adst_i[1]; e = e > 0.f ? e : 0.2f * e; sp[wave][1 * 64 + lane] = __expf(e);
                e = av.z + adst_i[2]; e = e > 0.f ? e : 0.2f * e; sp[wave][2 * 64 + lane] = __expf(e);
                e = av.w + adst_i[3]; e = e > 0.f ? e : 0.2f * e; sp[wave][3 * 64 + lane] = __expf(e);
            } else {
                float e = asrc[j] + adst_i[0];
                e = e > 0.f ? e : 0.2f * e;
                sp[wave][lane] = __expf(e);
            }
        }
        asm volatile("s_waitcnt lgkmcnt(0)" ::: "memory");

        int full = cnt & ~3;
        for (int idx = 0; idx < full; idx += 4) {
            int4   j4 = *(const int4*)  &sj[wave][idx];
            float4 p4 = *(const float4*)&sp[wave][head * 64 + idx];
            {
                float2 hv = *(const float2*)(fb + (size_t)j4.x * 128);
                ssum += p4.x; o0 = fmaf(p4.x, hv.x, o0); o1 = fmaf(p4.x, hv.y, o1);
            }
            {
                float2 hv = *(const float2*)(fb + (size_t)j4.y * 128);
                ssum += p4.y; o0 = fmaf(p4.y, hv.x, o0); o1 = fmaf(p4.y, hv.y, o1);
            }
            {
                float2 hv = *(const float2*)(fb + (size_t)j4.z * 128);
                ssum += p4.z; o0 = fmaf(p4.z, hv.x, o0); o1 = fmaf(p4.z, hv.y, o1);
            }
            {
                float2 hv = *(const float2*)(fb + (size_t)j4.w * 128);
                ssum += p4.w; o0 = fmaf(p4.w, hv.x, o0); o1 = fmaf(p4.w, hv.y, o1);
            }
        }
        for (int idx = full; idx < cnt; ++idx) {
            int j = sj[wave][idx];
            float aa = sp[wave][head * 64 + idx];
            float2 hv = *(const float2*)(fb + (size_t)j * 128);
            ssum += aa; o0 = fmaf(aa, hv.x, o0); o1 = fmaf(aa, hv.y, o1);
        }
    }

    float inv = 1.f / (ssum + 1e-16f);
    float r0 = o0 * inv + bias[c0];
    float r1 = o1 * inv + bias[c0 + 1];
    r0 = r0 > 0.f ? r0 : expm1f(r0);
    r1 = r1 > 0.f ? r1 : expm1f(r1);
    *(float2*)(out + (size_t)node * 128 + c0) = make_float2(r0, r1);
}

// ---------------- launch ----------------

extern "C" void kernel_launch(void* const* d_in, const int* in_sizes, int n_in,
                              void* d_out, int out_size, void* d_ws, size_t ws_size,
                              hipStream_t stream)
{
    const float* x    = (const float*)d_in[0];
    const int*   a    = (const int*)  d_in[1];
    const float* W1   = (const float*)d_in[2];
    const float* as1w = (const float*)d_in[3];
    const float* ad1w = (const float*)d_in[4];
    const float* b1   = (const float*)d_in[5];
    const float* W2   = (const float*)d_in[6];
    const float* as2w = (const float*)d_in[7];
    const float* ad2w = (const float*)d_in[8];
    const float* b2   = (const float*)d_in[9];

    const int N = in_sizes[0] / 128;
    const int E = in_sizes[1] / 2;
    const int* srcA = a;
    const int* dstA = a + E;

    char* ws = (char*)d_ws;
    size_t o = 0;
    auto alloc = [&](size_t bytes) -> void* {
        void* p = ws + o;
        o += (bytes + 255) & ~(size_t)255;
        return p;
    };
    float* hbuf = (float*)alloc((size_t)N * 128 * 4);
    float* hact = (float*)alloc((size_t)N * 128 * 4);
    float* as1  = (float*)alloc((size_t)N * 4 * 4);
    float* ad1  = (float*)alloc((size_t)N * 4 * 4);
    float* as2  = (float*)alloc((size_t)N * 4);
    float* ad2  = (float*)alloc((size_t)N * 4);
    int*   deg  = (int*)alloc((size_t)N * 4);
    int*   off  = (int*)alloc((size_t)(N + 1) * 4);
    int*   cur  = (int*)alloc((size_t)N * 4);
    int*   part = (int*)alloc(4096 * 4);
    int*   esrc = (int*)alloc((size_t)E * 4);

    hipMemsetAsync(deg, 0, (size_t)N * 4, stream);
    int eb = (E + 255) / 256;
    k_count<<<eb, 256, 0, stream>>>(dstA, deg, E);
    int NB = (N + 1023) / 1024;
    k_scanA<<<NB, 256, 0, stream>>>(deg, part, N);
    k_scanB<<<1, 1024, 0, stream>>>(part, NB, off + N, E);
    k_scanC<<<NB, 256, 0, stream>>>(deg, part, off, cur, N);
    k_scatter<<<eb, 256, 0, stream>>>(srcA, dstA, cur, esrc, E);

    // layer 1 (GEMM + fused attdot)
    k_gemm128<4><<<512, 256, 0, stream>>>(x, W1, as1w, ad1w, hbuf, as1, ad1, N);
    k_agg<4><<<(N + 3) / 4, 256, 0, stream>>>(hbuf, as1, ad1, off, esrc, b1, hact, N);

    // layer 2
    k_gemm128<1><<<512, 256, 0, stream>>>(hact, W2, as2w, ad2w, hbuf, as2, ad2, N);
    k_agg<1><<<(N + 3) / 4, 256, 0, stream>>>(hbuf, as2, ad2, off, esrc, b2, (float*)d_out, N);
}

// Round 4
// 560.303 us; speedup vs baseline: 3.8615x; 1.1894x over previous
//
#include <hip/hip_runtime.h>
#include <hip/hip_fp16.h>
#include <math.h>

// ---------------------------------------------------------------------------
// GAT graph encoder: 2x GATConv (PyG semantics, add_self_loops=False)
// R3->R4: gather payload compressed to fp16. The GEMM output Y is ONLY
// consumed by the random per-edge gather in k_agg (att-dots are computed in
// the GEMM epilogue from fp32 accumulators; agg outputs stay fp32), so Y is
// stored as fp16 [N,128] = 256 B/row -> halves gather + fetch + Y-write
// traffic. R3 showed k_agg fabric-bound: FETCH 441 MB @ 3.4 TB/s.
// ---------------------------------------------------------------------------

// ---------------- CSR build ----------------

__global__ void k_count(const int* __restrict__ dst, int* __restrict__ deg, int E) {
    int e = blockIdx.x * 256 + threadIdx.x;
    if (e < E) atomicAdd(&deg[dst[e]], 1);
}

__global__ void k_scanA(const int* __restrict__ deg, int* __restrict__ part, int N) {
    __shared__ int sd[256];
    int t = threadIdx.x;
    int base = blockIdx.x * 1024 + t * 4;
    int s = 0;
#pragma unroll
    for (int q = 0; q < 4; q++) { int idx = base + q; if (idx < N) s += deg[idx]; }
    sd[t] = s; __syncthreads();
    for (int o = 128; o > 0; o >>= 1) { if (t < o) sd[t] += sd[t + o]; __syncthreads(); }
    if (t == 0) part[blockIdx.x] = sd[0];
}

__global__ void k_scanB(int* __restrict__ part, int NB, int* __restrict__ offN, int E) {
    __shared__ int sd[1024];
    int t = threadIdx.x;
    int v = (t < NB) ? part[t] : 0;
    sd[t] = v; __syncthreads();
    for (int ofs = 1; ofs < 1024; ofs <<= 1) {
        int w = (t >= ofs) ? sd[t - ofs] : 0;
        __syncthreads();
        sd[t] += w;
        __syncthreads();
    }
    if (t < NB) part[t] = sd[t] - v;   // exclusive
    if (t == 0) *offN = E;
}

__global__ void k_scanC(const int* __restrict__ deg, const int* __restrict__ part,
                        int* __restrict__ off, int* __restrict__ cur, int N) {
    __shared__ int sd[256];
    int t = threadIdx.x;
    int base = blockIdx.x * 1024 + t * 4;
    int v[4]; int s = 0;
#pragma unroll
    for (int q = 0; q < 4; q++) { int idx = base + q; v[q] = (idx < N) ? deg[idx] : 0; s += v[q]; }
    sd[t] = s; __syncthreads();
    for (int ofs = 1; ofs < 256; ofs <<= 1) {
        int w = (t >= ofs) ? sd[t - ofs] : 0;
        __syncthreads();
        sd[t] += w;
        __syncthreads();
    }
    int run = sd[t] - s + part[blockIdx.x];
#pragma unroll
    for (int q = 0; q < 4; q++) {
        int idx = base + q;
        if (idx < N) { off[idx] = run; cur[idx] = run; run += v[q]; }
    }
}

__global__ void k_scatter(const int* __restrict__ src, const int* __restrict__ dst,
                          int* __restrict__ cur, int* __restrict__ esrc, int E) {
    int e = blockIdx.x * 256 + threadIdx.x;
    if (e < E) {
        int pos = atomicAdd(&cur[dst[e]], 1);
        esrc[pos] = src[e];
    }
}

// ---------------- GEMM + fused attention dots ----------------
// Y(fp16)[N,128] = X[N,128] @ W[128,128]; a_src/a_dst from fp32 accumulators.

#define FMA4(A, s, Wv) \
    A.x = fmaf(s, Wv.x, A.x); A.y = fmaf(s, Wv.y, A.y); \
    A.z = fmaf(s, Wv.z, A.z); A.w = fmaf(s, Wv.w, A.w);

template <int H>
__global__ __launch_bounds__(256) void k_gemm128(
    const float* __restrict__ X, const float* __restrict__ Wg,
    const float* __restrict__ att_s, const float* __restrict__ att_d,
    __half* __restrict__ Y, float* __restrict__ as_, float* __restrict__ ad_, int N)
{
    __shared__ float Wl[128 * 128];
    __shared__ float xs[32 * 128];
    int t = threadIdx.x;
    for (int i = t; i < 128 * 128 / 4; i += 256) ((float4*)Wl)[i] = ((const float4*)Wg)[i];

    const int tx = t & 31;
    const int ty = t >> 5;
    const int c0 = tx * 4;
    const float4 atts = ((const float4*)att_s)[tx];
    const float4 attd = ((const float4*)att_d)[tx];
    __syncthreads();

    for (int base = blockIdx.x * 32; base < N; base += gridDim.x * 32) {
        for (int i = t; i < 1024; i += 256) {
            int row = i >> 5, col4 = i & 31;
            int gr = base + row;
            float4 v = make_float4(0.f, 0.f, 0.f, 0.f);
            if (gr < N) v = ((const float4*)(X + (size_t)gr * 128))[col4];
            ((float4*)xs)[i] = v;
        }
        __syncthreads();

        float4 a0 = make_float4(0.f, 0.f, 0.f, 0.f);
        float4 a1 = a0, a2 = a0, a3 = a0;
        const float* xr = xs + ty * 4 * 128;
#pragma unroll 2
        for (int k = 0; k < 128; k += 4) {
            float4 x0 = *(const float4*)(xr + 0 * 128 + k);
            float4 x1 = *(const float4*)(xr + 1 * 128 + k);
            float4 x2 = *(const float4*)(xr + 2 * 128 + k);
            float4 x3 = *(const float4*)(xr + 3 * 128 + k);
            float4 w0 = *(const float4*)(Wl + (k + 0) * 128 + c0);
            float4 w1 = *(const float4*)(Wl + (k + 1) * 128 + c0);
            float4 w2 = *(const float4*)(Wl + (k + 2) * 128 + c0);
            float4 w3 = *(const float4*)(Wl + (k + 3) * 128 + c0);
            FMA4(a0, x0.x, w0) FMA4(a0, x0.y, w1) FMA4(a0, x0.z, w2) FMA4(a0, x0.w, w3)
            FMA4(a1, x1.x, w0) FMA4(a1, x1.y, w1) FMA4(a1, x1.z, w2) FMA4(a1, x1.w, w3)
            FMA4(a2, x2.x, w0) FMA4(a2, x2.y, w1) FMA4(a2, x2.z, w2) FMA4(a2, x2.w, w3)
            FMA4(a3, x3.x, w0) FMA4(a3, x3.y, w1) FMA4(a3, x3.z, w2) FMA4(a3, x3.w, w3)
        }
        int r0 = base + ty * 4;
#pragma unroll
        for (int i = 0; i < 4; i++) {
            float4 ai = (i == 0) ? a0 : (i == 1) ? a1 : (i == 2) ? a2 : a3;
            if (r0 + i < N) {
                __half2* yp = (__half2*)(Y + (size_t)(r0 + i) * 128 + c0);
                yp[0] = __floats2half2_rn(ai.x, ai.y);
                yp[1] = __floats2half2_rn(ai.z, ai.w);
            }
        }

        // fused attention dots (fp32): partial dot over 4 cols, shfl-reduce.
        float ps[4], pd[4];
#pragma unroll
        for (int i = 0; i < 4; i++) {
            float4 ai = (i == 0) ? a0 : (i == 1) ? a1 : (i == 2) ? a2 : a3;
            ps[i] = ai.x * atts.x + ai.y * atts.y + ai.z * atts.z + ai.w * atts.w;
            pd[i] = ai.x * attd.x + ai.y * attd.y + ai.z * attd.z + ai.w * attd.w;
        }
        const int levels = (H == 4) ? 4 : 16;
        for (int msk = 1; msk <= levels; msk <<= 1) {
#pragma unroll
            for (int i = 0; i < 4; i++) {
                ps[i] += __shfl_xor(ps[i], msk, 64);
                pd[i] += __shfl_xor(pd[i], msk, 64);
            }
        }
        if (H == 4) {
            if ((tx & 7) == 0) {
                int head = tx >> 3;
#pragma unroll
                for (int i = 0; i < 4; i++) {
                    if (r0 + i < N) {
                        as_[(size_t)(r0 + i) * 4 + head] = ps[i];
                        ad_[(size_t)(r0 + i) * 4 + head] = pd[i];
                    }
                }
            }
        } else {
            if (tx == 0) {
#pragma unroll
                for (int i = 0; i < 4; i++) {
                    if (r0 + i < N) { as_[r0 + i] = ps[i]; ad_[r0 + i] = pd[i]; }
                }
            }
        }
        __syncthreads();
    }
}

// ---------------- aggregation: one wave per dst node, fp16 gather ----------

template <int H>
__global__ __launch_bounds__(256) void k_agg(
    const __half* __restrict__ feat,  // [N,128] fp16
    const float* __restrict__ asrc,   // [N,H]
    const float* __restrict__ adst,   // [N,H]
    const int*   __restrict__ off,    // [N+1]
    const int*   __restrict__ esrc,   // [E]
    const float* __restrict__ bias,   // [128]
    float*       __restrict__ out,    // [N,128]
    int N)
{
    __shared__ __attribute__((aligned(16))) int   sj[4][64];
    __shared__ __attribute__((aligned(16))) float sp[4][64 * H];  // head-major

    int wave = threadIdx.x >> 6;
    int lane = threadIdx.x & 63;
    int node = (blockIdx.x * 256 + threadIdx.x) >> 6;
    if (node >= N) return;
    int beg = off[node], end = off[node + 1];

    float adst_i[H];
#pragma unroll
    for (int h = 0; h < H; h++) adst_i[h] = adst[(size_t)node * H + h];

    const int c0 = lane << 1;
    const int head = (H == 4) ? (lane >> 4) : 0;
    const __half* fb = feat + c0;
    float o0 = 0.f, o1 = 0.f, ssum = 0.f;

    for (int cbeg = beg; cbeg < end; cbeg += 64) {
        int cnt = end - cbeg; if (cnt > 64) cnt = 64;
        if (lane < cnt) {
            int j = esrc[cbeg + lane];
            sj[wave][lane] = j;
            if (H == 4) {
                float4 av = *(const float4*)(asrc + (size_t)j * 4);
                float e;
                e = av.x + adst_i[0]; e = e > 0.f ? e : 0.2f * e; sp[wave][0 * 64 + lane] = __expf(e);
                e = av.y + adst_i[1]; e = e > 0.f ? e : 0.2f * e; sp[wave][1 * 64 + lane] = __expf(e);
                e = av.z + adst_i[2]; e = e > 0.f ? e : 0.2f * e; sp[wave][2 * 64 + lane] = __expf(e);
                e = av.w + adst_i[3]; e = e > 0.f ? e : 0.2f * e; sp[wave][3 * 64 + lane] = __expf(e);
            } else {
                float e = asrc[j] + adst_i[0];
                e = e > 0.f ? e : 0.2f * e;
                sp[wave][lane] = __expf(e);
            }
        }
        asm volatile("s_waitcnt lgkmcnt(0)" ::: "memory");

        int full = cnt & ~3;
        for (int idx = 0; idx < full; idx += 4) {
            int4   j4 = *(const int4*)  &sj[wave][idx];
            float4 p4 = *(const float4*)&sp[wave][head * 64 + idx];
            {
                float2 hv = __half22float2(*(const __half2*)(fb + (size_t)j4.x * 128));
                ssum += p4.x; o0 = fmaf(p4.x, hv.x, o0); o1 = fmaf(p4.x, hv.y, o1);
            }
            {
                float2 hv = __half22float2(*(const __half2*)(fb + (size_t)j4.y * 128));
                ssum += p4.y; o0 = fmaf(p4.y, hv.x, o0); o1 = fmaf(p4.y, hv.y, o1);
            }
            {
                float2 hv = __half22float2(*(const __half2*)(fb + (size_t)j4.z * 128));
                ssum += p4.z; o0 = fmaf(p4.z, hv.x, o0); o1 = fmaf(p4.z, hv.y, o1);
            }
            {
                float2 hv = __half22float2(*(const __half2*)(fb + (size_t)j4.w * 128));
                ssum += p4.w; o0 = fmaf(p4.w, hv.x, o0); o1 = fmaf(p4.w, hv.y, o1);
            }
        }
        for (int idx = full; idx < cnt; ++idx) {
            int j = sj[wave][idx];
            float aa = sp[wave][head * 64 + idx];
            float2 hv = __half22float2(*(const __half2*)(fb + (size_t)j * 128));
            ssum += aa; o0 = fmaf(aa, hv.x, o0); o1 = fmaf(aa, hv.y, o1);
        }
    }

    float inv = 1.f / (ssum + 1e-16f);
    float r0 = o0 * inv + bias[c0];
    float r1 = o1 * inv + bias[c0 + 1];
    r0 = r0 > 0.f ? r0 : expm1f(r0);
    r1 = r1 > 0.f ? r1 : expm1f(r1);
    *(float2*)(out + (size_t)node * 128 + c0) = make_float2(r0, r1);
}

// ---------------- launch ----------------

extern "C" void kernel_launch(void* const* d_in, const int* in_sizes, int n_in,
                              void* d_out, int out_size, void* d_ws, size_t ws_size,
                              hipStream_t stream)
{
    const float* x    = (const float*)d_in[0];
    const int*   a    = (const int*)  d_in[1];
    const float* W1   = (const float*)d_in[2];
    const float* as1w = (const float*)d_in[3];
    const float* ad1w = (const float*)d_in[4];
    const float* b1   = (const float*)d_in[5];
    const float* W2   = (const float*)d_in[6];
    const float* as2w = (const float*)d_in[7];
    const float* ad2w = (const float*)d_in[8];
    const float* b2   = (const float*)d_in[9];

    const int N = in_sizes[0] / 128;
    const int E = in_sizes[1] / 2;
    const int* srcA = a;
    const int* dstA = a + E;

    char* ws = (char*)d_ws;
    size_t o = 0;
    auto alloc = [&](size_t bytes) -> void* {
        void* p = ws + o;
        o += (bytes + 255) & ~(size_t)255;
        return p;
    };
    __half* hbuf = (__half*)alloc((size_t)N * 128 * 2);  // fp16 gather payload
    float*  hact = (float*) alloc((size_t)N * 128 * 4);  // elu(gat1), GEMM2 input
    float*  as1  = (float*) alloc((size_t)N * 4 * 4);
    float*  ad1  = (float*) alloc((size_t)N * 4 * 4);
    float*  as2  = (float*) alloc((size_t)N * 4);
    float*  ad2  = (float*) alloc((size_t)N * 4);
    int*    deg  = (int*)   alloc((size_t)N * 4);
    int*    off  = (int*)   alloc((size_t)(N + 1) * 4);
    int*    cur  = (int*)   alloc((size_t)N * 4);
    int*    part = (int*)   alloc(4096 * 4);
    int*    esrc = (int*)   alloc((size_t)E * 4);

    hipMemsetAsync(deg, 0, (size_t)N * 4, stream);
    int eb = (E + 255) / 256;
    k_count<<<eb, 256, 0, stream>>>(dstA, deg, E);
    int NB = (N + 1023) / 1024;
    k_scanA<<<NB, 256, 0, stream>>>(deg, part, N);
    k_scanB<<<1, 1024, 0, stream>>>(part, NB, off + N, E);
    k_scanC<<<NB, 256, 0, stream>>>(deg, part, off, cur, N);
    k_scatter<<<eb, 256, 0, stream>>>(srcA, dstA, cur, esrc, E);

    // layer 1 (GEMM + fused attdot, fp16 Y)
    k_gemm128<4><<<512, 256, 0, stream>>>(x, W1, as1w, ad1w, hbuf, as1, ad1, N);
    k_agg<4><<<(N + 3) / 4, 256, 0, stream>>>(hbuf, as1, ad1, off, esrc, b1, hact, N);

    // layer 2
    k_gemm128<1><<<512, 256, 0, stream>>>(hact, W2, as2w, ad2w, hbuf, as2, ad2, N);
    k_agg<1><<<(N + 3) / 4, 256, 0, stream>>>(hbuf, as2, ad2, off, esrc, b2, (float*)d_out, N);
}

// Round 5
// 441.353 us; speedup vs baseline: 4.9022x; 1.2695x over previous
//
#include <hip/hip_runtime.h>
#include <hip/hip_fp16.h>
#include <math.h>

// ---------------------------------------------------------------------------
// GAT graph encoder: 2x GATConv (PyG semantics, add_self_loops=False)
// R4->R5: CSR build rewritten. R4's k_scatter wrote 105 MB for a 6.4 MB
// array (random 4B stores -> 64B-line writeback x8 XCDs) at ~1 TB/s = 122 us.
// New build: bucket (128 nodes) counting sort with block-staged reservations:
//   k_hist -> k_bscan -> k_binscatter (contiguous packed runs) -> k_bsort
//   (per-bucket LDS counting sort; esrc region stays in one CU's L2; also
//   emits off[]). All writes coalesced or XCD-local.
// ---------------------------------------------------------------------------

// ---------------- CSR build ----------------

// Pass A: global bucket histogram (bucket = dst >> 7).
__global__ __launch_bounds__(256) void k_hist(const int* __restrict__ dst,
                                              int* __restrict__ bcnt, int E, int NBUCK) {
    __shared__ int lh[1024];
    int t = threadIdx.x;
    for (int i = t; i < NBUCK; i += 256) lh[i] = 0;
    __syncthreads();
    for (int e = blockIdx.x * 256 + t; e < E; e += gridDim.x * 256)
        atomicAdd(&lh[dst[e] >> 7], 1);
    __syncthreads();
    for (int i = t; i < NBUCK; i += 256) {
        int c = lh[i];
        if (c) atomicAdd(&bcnt[i], c);
    }
}

// Pass B: exclusive scan of bucket counts (NBUCK <= 1024); init cursors.
__global__ void k_bscan(const int* __restrict__ bcnt, int* __restrict__ bbase,
                        int* __restrict__ bcur, int* __restrict__ off,
                        int NBUCK, int N, int E) {
    __shared__ int sd[1024];
    int t = threadIdx.x;
    int v = (t < NBUCK) ? bcnt[t] : 0;
    sd[t] = v; __syncthreads();
    for (int ofs = 1; ofs < 1024; ofs <<= 1) {
        int w = (t >= ofs) ? sd[t - ofs] : 0;
        __syncthreads();
        sd[t] += w;
        __syncthreads();
    }
    if (t < NBUCK) { int ex = sd[t] - v; bbase[t] = ex; bcur[t] = ex; }
    if (t == 0) { bbase[NBUCK] = E; off[N] = E; }
}

// Pass C: tile (8192 edges) -> LDS histogram -> one reservation atomic per
// bucket per tile -> write packed (src<<7 | dst&127) in contiguous runs.
__global__ __launch_bounds__(256) void k_binscatter(
    const int* __restrict__ src, const int* __restrict__ dst,
    int* __restrict__ bcur, int* __restrict__ tmp, int E, int NBUCK) {
    __shared__ int lh[1024], lbase[1024];
    int t = threadIdx.x;
    for (int i = t; i < NBUCK; i += 256) lh[i] = 0;
    __syncthreads();
    int tbeg = blockIdx.x * 8192;
    int tend = tbeg + 8192; if (tend > E) tend = E;
    for (int e = tbeg + t; e < tend; e += 256) atomicAdd(&lh[dst[e] >> 7], 1);
    __syncthreads();
    for (int i = t; i < NBUCK; i += 256) {
        int c = lh[i];
        lbase[i] = c ? atomicAdd(&bcur[i], c) : 0;
        lh[i] = 0;
    }
    __syncthreads();
    for (int e = tbeg + t; e < tend; e += 256) {
        int d = dst[e];
        int b = d >> 7;
        int r = atomicAdd(&lh[b], 1);
        tmp[lbase[b] + r] = (src[e] << 7) | (d & 127);
    }
}

// Pass D: one block per bucket. 128-bin LDS counting sort (streamed twice
// from global, no capacity limit); writes off[] and esrc[].
__global__ __launch_bounds__(256) void k_bsort(
    const int* __restrict__ tmp, const int* __restrict__ bbase,
    int* __restrict__ off, int* __restrict__ esrc, int N) {
    __shared__ int h[128], hs[128], cur[128];
    int b = blockIdx.x, t = threadIdx.x;
    int base = bbase[b];
    int cnt  = bbase[b + 1] - base;
    int node0 = b << 7;
    if (t < 128) h[t] = 0;
    __syncthreads();
    for (int i = t; i < cnt; i += 256) atomicAdd(&h[tmp[base + i] & 127], 1);
    __syncthreads();
    if (t < 128) hs[t] = h[t];
    __syncthreads();
    for (int ofs = 1; ofs < 128; ofs <<= 1) {
        int w = (t < 128 && t >= ofs) ? hs[t - ofs] : 0;
        __syncthreads();
        if (t < 128) hs[t] += w;
        __syncthreads();
    }
    if (t < 128) {
        int ex = hs[t] - h[t];                 // exclusive prefix within bucket
        if (node0 + t < N) off[node0 + t] = base + ex;
        cur[t] = base + ex;
    }
    __syncthreads();
    for (int i = t; i < cnt; i += 256) {
        int p = tmp[base + i];
        int pos = atomicAdd(&cur[p & 127], 1);
        esrc[pos] = p >> 7;
    }
}

// ---------------- GEMM + fused attention dots ----------------
// Y(fp16)[N,128] = X[N,128] @ W[128,128]; a_src/a_dst from fp32 accumulators.

#define FMA4(A, s, Wv) \
    A.x = fmaf(s, Wv.x, A.x); A.y = fmaf(s, Wv.y, A.y); \
    A.z = fmaf(s, Wv.z, A.z); A.w = fmaf(s, Wv.w, A.w);

template <int H>
__global__ __launch_bounds__(256) void k_gemm128(
    const float* __restrict__ X, const float* __restrict__ Wg,
    const float* __restrict__ att_s, const float* __restrict__ att_d,
    __half* __restrict__ Y, float* __restrict__ as_, float* __restrict__ ad_, int N)
{
    __shared__ float Wl[128 * 128];
    __shared__ float xs[32 * 128];
    int t = threadIdx.x;
    for (int i = t; i < 128 * 128 / 4; i += 256) ((float4*)Wl)[i] = ((const float4*)Wg)[i];

    const int tx = t & 31;
    const int ty = t >> 5;
    const int c0 = tx * 4;
    const float4 atts = ((const float4*)att_s)[tx];
    const float4 attd = ((const float4*)att_d)[tx];
    __syncthreads();

    for (int base = blockIdx.x * 32; base < N; base += gridDim.x * 32) {
        for (int i = t; i < 1024; i += 256) {
            int row = i >> 5, col4 = i & 31;
            int gr = base + row;
            float4 v = make_float4(0.f, 0.f, 0.f, 0.f);
            if (gr < N) v = ((const float4*)(X + (size_t)gr * 128))[col4];
            ((float4*)xs)[i] = v;
        }
        __syncthreads();

        float4 a0 = make_float4(0.f, 0.f, 0.f, 0.f);
        float4 a1 = a0, a2 = a0, a3 = a0;
        const float* xr = xs + ty * 4 * 128;
#pragma unroll 2
        for (int k = 0; k < 128; k += 4) {
            float4 x0 = *(const float4*)(xr + 0 * 128 + k);
            float4 x1 = *(const float4*)(xr + 1 * 128 + k);
            float4 x2 = *(const float4*)(xr + 2 * 128 + k);
            float4 x3 = *(const float4*)(xr + 3 * 128 + k);
            float4 w0 = *(const float4*)(Wl + (k + 0) * 128 + c0);
            float4 w1 = *(const float4*)(Wl + (k + 1) * 128 + c0);
            float4 w2 = *(const float4*)(Wl + (k + 2) * 128 + c0);
            float4 w3 = *(const float4*)(Wl + (k + 3) * 128 + c0);
            FMA4(a0, x0.x, w0) FMA4(a0, x0.y, w1) FMA4(a0, x0.z, w2) FMA4(a0, x0.w, w3)
            FMA4(a1, x1.x, w0) FMA4(a1, x1.y, w1) FMA4(a1, x1.z, w2) FMA4(a1, x1.w, w3)
            FMA4(a2, x2.x, w0) FMA4(a2, x2.y, w1) FMA4(a2, x2.z, w2) FMA4(a2, x2.w, w3)
            FMA4(a3, x3.x, w0) FMA4(a3, x3.y, w1) FMA4(a3, x3.z, w2) FMA4(a3, x3.w, w3)
        }
        int r0 = base + ty * 4;
#pragma unroll
        for (int i = 0; i < 4; i++) {
            float4 ai = (i == 0) ? a0 : (i == 1) ? a1 : (i == 2) ? a2 : a3;
            if (r0 + i < N) {
                __half2* yp = (__half2*)(Y + (size_t)(r0 + i) * 128 + c0);
                yp[0] = __floats2half2_rn(ai.x, ai.y);
                yp[1] = __floats2half2_rn(ai.z, ai.w);
            }
        }

        // fused attention dots (fp32): partial dot over 4 cols, shfl-reduce.
        float ps[4], pd[4];
#pragma unroll
        for (int i = 0; i < 4; i++) {
            float4 ai = (i == 0) ? a0 : (i == 1) ? a1 : (i == 2) ? a2 : a3;
            ps[i] = ai.x * atts.x + ai.y * atts.y + ai.z * atts.z + ai.w * atts.w;
            pd[i] = ai.x * attd.x + ai.y * attd.y + ai.z * attd.z + ai.w * attd.w;
        }
        const int levels = (H == 4) ? 4 : 16;
        for (int msk = 1; msk <= levels; msk <<= 1) {
#pragma unroll
            for (int i = 0; i < 4; i++) {
                ps[i] += __shfl_xor(ps[i], msk, 64);
                pd[i] += __shfl_xor(pd[i], msk, 64);
            }
        }
        if (H == 4) {
            if ((tx & 7) == 0) {
                int head = tx >> 3;
#pragma unroll
                for (int i = 0; i < 4; i++) {
                    if (r0 + i < N) {
                        as_[(size_t)(r0 + i) * 4 + head] = ps[i];
                        ad_[(size_t)(r0 + i) * 4 + head] = pd[i];
                    }
                }
            }
        } else {
            if (tx == 0) {
#pragma unroll
                for (int i = 0; i < 4; i++) {
                    if (r0 + i < N) { as_[r0 + i] = ps[i]; ad_[r0 + i] = pd[i]; }
                }
            }
        }
        __syncthreads();
    }
}

// ---------------- aggregation: one wave per dst node, fp16 gather ----------

template <int H>
__global__ __launch_bounds__(256) void k_agg(
    const __half* __restrict__ feat,  // [N,128] fp16
    const float* __restrict__ asrc,   // [N,H]
    const float* __restrict__ adst,   // [N,H]
    const int*   __restrict__ off,    // [N+1]
    const int*   __restrict__ esrc,   // [E]
    const float* __restrict__ bias,   // [128]
    float*       __restrict__ out,    // [N,128]
    int N)
{
    __shared__ __attribute__((aligned(16))) int   sj[4][64];
    __shared__ __attribute__((aligned(16))) float sp[4][64 * H];  // head-major

    int wave = threadIdx.x >> 6;
    int lane = threadIdx.x & 63;
    int node = (blockIdx.x * 256 + threadIdx.x) >> 6;
    if (node >= N) return;
    int beg = off[node], end = off[node + 1];

    float adst_i[H];
#pragma unroll
    for (int h = 0; h < H; h++) adst_i[h] = adst[(size_t)node * H + h];

    const int c0 = lane << 1;
    const int head = (H == 4) ? (lane >> 4) : 0;
    const __half* fb = feat + c0;
    float o0 = 0.f, o1 = 0.f, ssum = 0.f;

    for (int cbeg = beg; cbeg < end; cbeg += 64) {
        int cnt = end - cbeg; if (cnt > 64) cnt = 64;
        if (lane < cnt) {
            int j = esrc[cbeg + lane];
            sj[wave][lane] = j;
            if (H == 4) {
                float4 av = *(const float4*)(asrc + (size_t)j * 4);
                float e;
                e = av.x + adst_i[0]; e = e > 0.f ? e : 0.2f * e; sp[wave][0 * 64 + lane] = __expf(e);
                e = av.y + adst_i[1]; e = e > 0.f ? e : 0.2f * e; sp[wave][1 * 64 + lane] = __expf(e);
                e = av.z + adst_i[2]; e = e > 0.f ? e : 0.2f * e; sp[wave][2 * 64 + lane] = __expf(e);
                e = av.w + adst_i[3]; e = e > 0.f ? e : 0.2f * e; sp[wave][3 * 64 + lane] = __expf(e);
            } else {
                float e = asrc[j] + adst_i[0];
                e = e > 0.f ? e : 0.2f * e;
                sp[wave][lane] = __expf(e);
            }
        }
        asm volatile("s_waitcnt lgkmcnt(0)" ::: "memory");

        int full = cnt & ~3;
        for (int idx = 0; idx < full; idx += 4) {
            int4   j4 = *(const int4*)  &sj[wave][idx];
            float4 p4 = *(const float4*)&sp[wave][head * 64 + idx];
            {
                float2 hv = __half22float2(*(const __half2*)(fb + (size_t)j4.x * 128));
                ssum += p4.x; o0 = fmaf(p4.x, hv.x, o0); o1 = fmaf(p4.x, hv.y, o1);
            }
            {
                float2 hv = __half22float2(*(const __half2*)(fb + (size_t)j4.y * 128));
                ssum += p4.y; o0 = fmaf(p4.y, hv.x, o0); o1 = fmaf(p4.y, hv.y, o1);
            }
            {
                float2 hv = __half22float2(*(const __half2*)(fb + (size_t)j4.z * 128));
                ssum += p4.z; o0 = fmaf(p4.z, hv.x, o0); o1 = fmaf(p4.z, hv.y, o1);
            }
            {
                float2 hv = __half22float2(*(const __half2*)(fb + (size_t)j4.w * 128));
                ssum += p4.w; o0 = fmaf(p4.w, hv.x, o0); o1 = fmaf(p4.w, hv.y, o1);
            }
        }
        for (int idx = full; idx < cnt; ++idx) {
            int j = sj[wave][idx];
            float aa = sp[wave][head * 64 + idx];
            float2 hv = __half22float2(*(const __half2*)(fb + (size_t)j * 128));
            ssum += aa; o0 = fmaf(aa, hv.x, o0); o1 = fmaf(aa, hv.y, o1);
        }
    }

    float inv = 1.f / (ssum + 1e-16f);
    float r0 = o0 * inv + bias[c0];
    float r1 = o1 * inv + bias[c0 + 1];
    r0 = r0 > 0.f ? r0 : expm1f(r0);
    r1 = r1 > 0.f ? r1 : expm1f(r1);
    *(float2*)(out + (size_t)node * 128 + c0) = make_float2(r0, r1);
}

// ---------------- launch ----------------

extern "C" void kernel_launch(void* const* d_in, const int* in_sizes, int n_in,
                              void* d_out, int out_size, void* d_ws, size_t ws_size,
                              hipStream_t stream)
{
    const float* x    = (const float*)d_in[0];
    const int*   a    = (const int*)  d_in[1];
    const float* W1   = (const float*)d_in[2];
    const float* as1w = (const float*)d_in[3];
    const float* ad1w = (const float*)d_in[4];
    const float* b1   = (const float*)d_in[5];
    const float* W2   = (const float*)d_in[6];
    const float* as2w = (const float*)d_in[7];
    const float* ad2w = (const float*)d_in[8];
    const float* b2   = (const float*)d_in[9];

    const int N = in_sizes[0] / 128;
    const int E = in_sizes[1] / 2;
    const int* srcA = a;
    const int* dstA = a + E;
    const int NBUCK = (N + 127) >> 7;   // 128 nodes per bucket (<=1024 buckets)

    char* ws = (char*)d_ws;
    size_t o = 0;
    auto alloc = [&](size_t bytes) -> void* {
        void* p = ws + o;
        o += (bytes + 255) & ~(size_t)255;
        return p;
    };
    __half* hbuf  = (__half*)alloc((size_t)N * 128 * 2);  // fp16 gather payload
    float*  hact  = (float*) alloc((size_t)N * 128 * 4);  // elu(gat1), GEMM2 input
    float*  as1   = (float*) alloc((size_t)N * 4 * 4);
    float*  ad1   = (float*) alloc((size_t)N * 4 * 4);
    float*  as2   = (float*) alloc((size_t)N * 4);
    float*  ad2   = (float*) alloc((size_t)N * 4);
    int*    off   = (int*)   alloc((size_t)(N + 1) * 4);
    int*    esrc  = (int*)   alloc((size_t)E * 4);
    int*    tmp   = (int*)   alloc((size_t)E * 4);        // bucket-grouped packed edges
    int*    bcnt  = (int*)   alloc(1024 * 4);
    int*    bbase = (int*)   alloc(1025 * 4);
    int*    bcur  = (int*)   alloc(1024 * 4);

    // CSR build (rebuilt each launch; ws is re-poisoned)
    hipMemsetAsync(bcnt, 0, (size_t)NBUCK * 4, stream);
    k_hist<<<256, 256, 0, stream>>>(dstA, bcnt, E, NBUCK);
    k_bscan<<<1, 1024, 0, stream>>>(bcnt, bbase, bcur, off, NBUCK, N, E);
    k_binscatter<<<(E + 8191) / 8192, 256, 0, stream>>>(srcA, dstA, bcur, tmp, E, NBUCK);
    k_bsort<<<NBUCK, 256, 0, stream>>>(tmp, bbase, off, esrc, N);

    // layer 1 (GEMM + fused attdot, fp16 Y)
    k_gemm128<4><<<512, 256, 0, stream>>>(x, W1, as1w, ad1w, hbuf, as1, ad1, N);
    k_agg<4><<<(N + 3) / 4, 256, 0, stream>>>(hbuf, as1, ad1, off, esrc, b1, hact, N);

    // layer 2
    k_gemm128<1><<<512, 256, 0, stream>>>(hact, W2, as2w, ad2w, hbuf, as2, ad2, N);
    k_agg<1><<<(N + 3) / 4, 256, 0, stream>>>(hbuf, as2, ad2, off, esrc, b2, (float*)d_out, N);
}

// Round 6
// 363.998 us; speedup vs baseline: 5.9440x; 1.2125x over previous
//
#include <hip/hip_runtime.h>
#include <hip/hip_fp16.h>
#include <math.h>

// ---------------------------------------------------------------------------
// GAT graph encoder: 2x GATConv (PyG semantics, add_self_loops=False)
// R5->R6: GEMMs moved to MFMA (v_mfma_f32_16x16x32_f16, fp32 accum).
//   Inputs cast to fp16 (pipeline already fp16-tolerant per R4). 4 waves per
//   block, 64-row tile; W fp16 in LDS; per-wave B-fragments (8 ntiles x 4
//   ksteps) preloaded into 128 VGPRs -> K-loop = 1 ds_read_b128 + 8 MFMA per
//   kstep. Att dots reduced in-register from C-layout accs. hact now fp16.
// CSR build (R5) and k_agg (R3/R4) unchanged.
// ---------------------------------------------------------------------------

typedef _Float16 f16x8 __attribute__((ext_vector_type(8)));
typedef float    f32x4 __attribute__((ext_vector_type(4)));

// ---------------- CSR build ----------------

__global__ __launch_bounds__(256) void k_hist(const int* __restrict__ dst,
                                              int* __restrict__ bcnt, int E, int NBUCK) {
    __shared__ int lh[1024];
    int t = threadIdx.x;
    for (int i = t; i < NBUCK; i += 256) lh[i] = 0;
    __syncthreads();
    for (int e = blockIdx.x * 256 + t; e < E; e += gridDim.x * 256)
        atomicAdd(&lh[dst[e] >> 7], 1);
    __syncthreads();
    for (int i = t; i < NBUCK; i += 256) {
        int c = lh[i];
        if (c) atomicAdd(&bcnt[i], c);
    }
}

__global__ void k_bscan(const int* __restrict__ bcnt, int* __restrict__ bbase,
                        int* __restrict__ bcur, int* __restrict__ off,
                        int NBUCK, int N, int E) {
    __shared__ int sd[1024];
    int t = threadIdx.x;
    int v = (t < NBUCK) ? bcnt[t] : 0;
    sd[t] = v; __syncthreads();
    for (int ofs = 1; ofs < 1024; ofs <<= 1) {
        int w = (t >= ofs) ? sd[t - ofs] : 0;
        __syncthreads();
        sd[t] += w;
        __syncthreads();
    }
    if (t < NBUCK) { int ex = sd[t] - v; bbase[t] = ex; bcur[t] = ex; }
    if (t == 0) { bbase[NBUCK] = E; off[N] = E; }
}

__global__ __launch_bounds__(256) void k_binscatter(
    const int* __restrict__ src, const int* __restrict__ dst,
    int* __restrict__ bcur, int* __restrict__ tmp, int E, int NBUCK) {
    __shared__ int lh[1024], lbase[1024];
    int t = threadIdx.x;
    for (int i = t; i < NBUCK; i += 256) lh[i] = 0;
    __syncthreads();
    int tbeg = blockIdx.x * 8192;
    int tend = tbeg + 8192; if (tend > E) tend = E;
    for (int e = tbeg + t; e < tend; e += 256) atomicAdd(&lh[dst[e] >> 7], 1);
    __syncthreads();
    for (int i = t; i < NBUCK; i += 256) {
        int c = lh[i];
        lbase[i] = c ? atomicAdd(&bcur[i], c) : 0;
        lh[i] = 0;
    }
    __syncthreads();
    for (int e = tbeg + t; e < tend; e += 256) {
        int d = dst[e];
        int b = d >> 7;
        int r = atomicAdd(&lh[b], 1);
        tmp[lbase[b] + r] = (src[e] << 7) | (d & 127);
    }
}

__global__ __launch_bounds__(256) void k_bsort(
    const int* __restrict__ tmp, const int* __restrict__ bbase,
    int* __restrict__ off, int* __restrict__ esrc, int N) {
    __shared__ int h[128], hs[128], cur[128];
    int b = blockIdx.x, t = threadIdx.x;
    int base = bbase[b];
    int cnt  = bbase[b + 1] - base;
    int node0 = b << 7;
    if (t < 128) h[t] = 0;
    __syncthreads();
    for (int i = t; i < cnt; i += 256) atomicAdd(&h[tmp[base + i] & 127], 1);
    __syncthreads();
    if (t < 128) hs[t] = h[t];
    __syncthreads();
    for (int ofs = 1; ofs < 128; ofs <<= 1) {
        int w = (t < 128 && t >= ofs) ? hs[t - ofs] : 0;
        __syncthreads();
        if (t < 128) hs[t] += w;
        __syncthreads();
    }
    if (t < 128) {
        int ex = hs[t] - h[t];
        if (node0 + t < N) off[node0 + t] = base + ex;
        cur[t] = base + ex;
    }
    __syncthreads();
    for (int i = t; i < cnt; i += 256) {
        int p = tmp[base + i];
        int pos = atomicAdd(&cur[p & 127], 1);
        esrc[pos] = p >> 7;
    }
}

// ---------------- MFMA GEMM + fused attention dots ----------------
// Y(fp16)[N,128] = cast16(X[N,128]) @ cast16(W[128,128]); fp32 accum.
// A-frag: m=lane&15 (row), k=(lane>>4)*8+j. B-frag: n=lane&15 (col), same k.
// C/D: col=lane&15, row=(lane>>4)*4+reg.

template <int H, typename TI>
__global__ __launch_bounds__(256, 2) void k_gemm_mfma(
    const TI* __restrict__ X, const float* __restrict__ Wg,
    const float* __restrict__ att_s, const float* __restrict__ att_d,
    __half* __restrict__ Y, float* __restrict__ as_, float* __restrict__ ad_, int N)
{
    __shared__ _Float16 Wh[128 * 128];   // [k][col]
    __shared__ _Float16 Xh[64][136];     // +8 pad: breaks 256B-stride bank clash
    const int t = threadIdx.x;
    const int lane = t & 63;
    const int wv = t >> 6;
    const int m = lane & 15;
    const int q = lane >> 4;

    // stage W fp32 -> fp16 (coalesced float4 reads)
    for (int i = t; i < 128 * 128 / 4; i += 256) {
        float4 w4 = ((const float4*)Wg)[i];
        _Float16* d = &Wh[i * 4];
        d[0] = (_Float16)w4.x; d[1] = (_Float16)w4.y;
        d[2] = (_Float16)w4.z; d[3] = (_Float16)w4.w;
    }
    __syncthreads();

    // preload all B fragments into registers (8 ntiles x 4 ksteps x 4 VGPR)
    f16x8 bfr[8][4];
#pragma unroll
    for (int nt = 0; nt < 8; nt++) {
#pragma unroll
        for (int ks = 0; ks < 4; ks++) {
            f16x8 b;
#pragma unroll
            for (int j = 0; j < 8; j++)
                b[j] = Wh[(ks * 32 + q * 8 + j) * 128 + nt * 16 + m];
            bfr[nt][ks] = b;
        }
    }
    float atts_v[8], attd_v[8];
#pragma unroll
    for (int nt = 0; nt < 8; nt++) {
        atts_v[nt] = att_s[nt * 16 + m];
        attd_v[nt] = att_d[nt * 16 + m];
    }

    for (int base = blockIdx.x * 64; base < N; base += gridDim.x * 64) {
        // stage 64 rows of X -> fp16 LDS (1024 chunks of 8 halfs, 4/thread)
        for (int i = t; i < 1024; i += 256) {
            int r = i >> 4, c8 = i & 15;
            int gr = base + r;
            _Float16* d = &Xh[r][c8 * 8];
            if (gr < N) {
                if constexpr (sizeof(TI) == 4) {
                    const float4* s = (const float4*)((const float*)X + (size_t)gr * 128 + c8 * 8);
                    float4 x0 = s[0], x1 = s[1];
                    d[0] = (_Float16)x0.x; d[1] = (_Float16)x0.y;
                    d[2] = (_Float16)x0.z; d[3] = (_Float16)x0.w;
                    d[4] = (_Float16)x1.x; d[5] = (_Float16)x1.y;
                    d[6] = (_Float16)x1.z; d[7] = (_Float16)x1.w;
                } else {
                    *(uint4*)d = *(const uint4*)((const __half*)X + (size_t)gr * 128 + c8 * 8);
                }
            } else {
                uint4 z; z.x = 0; z.y = 0; z.z = 0; z.w = 0;
                *(uint4*)d = z;
            }
        }
        __syncthreads();

        const int rowb = base + wv * 16;
        f32x4 acc[8];
#pragma unroll
        for (int nt = 0; nt < 8; nt++) { acc[nt][0] = 0.f; acc[nt][1] = 0.f; acc[nt][2] = 0.f; acc[nt][3] = 0.f; }
#pragma unroll
        for (int ks = 0; ks < 4; ks++) {
            f16x8 af = *(const f16x8*)&Xh[wv * 16 + m][ks * 32 + q * 8];
#pragma unroll
            for (int nt = 0; nt < 8; nt++)
                acc[nt] = __builtin_amdgcn_mfma_f32_16x16x32_f16(af, bfr[nt][ks], acc[nt], 0, 0, 0);
        }

        // Y writes (fp16 scalar stores; C-layout)
#pragma unroll
        for (int nt = 0; nt < 8; nt++) {
#pragma unroll
            for (int i = 0; i < 4; i++) {
                int r = rowb + q * 4 + i;
                if (r < N) Y[(size_t)r * 128 + nt * 16 + m] = __float2half(acc[nt][i]);
            }
        }

        // fused attention dots: per-lane partials, butterfly over the 16 cols
        if (H == 4) {
            float ph[4][4], pdv[4][4];
#pragma unroll
            for (int h = 0; h < 4; h++)
#pragma unroll
                for (int i = 0; i < 4; i++) {
                    ph[h][i]  = acc[2 * h][i] * atts_v[2 * h] + acc[2 * h + 1][i] * atts_v[2 * h + 1];
                    pdv[h][i] = acc[2 * h][i] * attd_v[2 * h] + acc[2 * h + 1][i] * attd_v[2 * h + 1];
                }
#pragma unroll
            for (int lvl = 0; lvl < 4; lvl++) {
                const int msk = 1 << lvl;
#pragma unroll
                for (int h = 0; h < 4; h++)
#pragma unroll
                    for (int i = 0; i < 4; i++) {
                        ph[h][i]  += __shfl_xor(ph[h][i], msk, 64);
                        pdv[h][i] += __shfl_xor(pdv[h][i], msk, 64);
                    }
            }
            if (m == 0) {
#pragma unroll
                for (int i = 0; i < 4; i++) {
                    int r = rowb + q * 4 + i;
                    if (r < N) {
#pragma unroll
                        for (int h = 0; h < 4; h++) {
                            as_[(size_t)r * 4 + h] = ph[h][i];
                            ad_[(size_t)r * 4 + h] = pdv[h][i];
                        }
                    }
                }
            }
        } else {
            float ps[4], pdv[4];
#pragma unroll
            for (int i = 0; i < 4; i++) {
                float s = 0.f, dsum = 0.f;
#pragma unroll
                for (int nt = 0; nt < 8; nt++) {
                    s    += acc[nt][i] * atts_v[nt];
                    dsum += acc[nt][i] * attd_v[nt];
                }
                ps[i] = s; pdv[i] = dsum;
            }
#pragma unroll
            for (int lvl = 0; lvl < 4; lvl++) {
                const int msk = 1 << lvl;
#pragma unroll
                for (int i = 0; i < 4; i++) {
                    ps[i]  += __shfl_xor(ps[i], msk, 64);
                    pdv[i] += __shfl_xor(pdv[i], msk, 64);
                }
            }
            if (m == 0) {
#pragma unroll
                for (int i = 0; i < 4; i++) {
                    int r = rowb + q * 4 + i;
                    if (r < N) { as_[r] = ps[i]; ad_[r] = pdv[i]; }
                }
            }
        }
        __syncthreads();   // protect Xh before next tile's staging
    }
}

// ---------------- aggregation: one wave per dst node, fp16 gather ----------

template <int H, typename TO>
__global__ __launch_bounds__(256) void k_agg(
    const __half* __restrict__ feat,  // [N,128] fp16
    const float* __restrict__ asrc,   // [N,H]
    const float* __restrict__ adst,   // [N,H]
    const int*   __restrict__ off,    // [N+1]
    const int*   __restrict__ esrc,   // [E]
    const float* __restrict__ bias,   // [128]
    TO*          __restrict__ out,    // [N,128]
    int N)
{
    __shared__ __attribute__((aligned(16))) int   sj[4][64];
    __shared__ __attribute__((aligned(16))) float sp[4][64 * H];  // head-major

    int wave = threadIdx.x >> 6;
    int lane = threadIdx.x & 63;
    int node = (blockIdx.x * 256 + threadIdx.x) >> 6;
    if (node >= N) return;
    int beg = off[node], end = off[node + 1];

    float adst_i[H];
#pragma unroll
    for (int h = 0; h < H; h++) adst_i[h] = adst[(size_t)node * H + h];

    const int c0 = lane << 1;
    const int head = (H == 4) ? (lane >> 4) : 0;
    const __half* fb = feat + c0;
    float o0 = 0.f, o1 = 0.f, ssum = 0.f;

    for (int cbeg = beg; cbeg < end; cbeg += 64) {
        int cnt = end - cbeg; if (cnt > 64) cnt = 64;
        if (lane < cnt) {
            int j = esrc[cbeg + lane];
            sj[wave][lane] = j;
            if (H == 4) {
                float4 av = *(const float4*)(asrc + (size_t)j * 4);
                float e;
                e = av.x + adst_i[0]; e = e > 0.f ? e : 0.2f * e; sp[wave][0 * 64 + lane] = __expf(e);
                e = av.y + adst_i[1]; e = e > 0.f ? e : 0.2f * e; sp[wave][1 * 64 + lane] = __expf(e);
                e = av.z + adst_i[2]; e = e > 0.f ? e : 0.2f * e; sp[wave][2 * 64 + lane] = __expf(e);
                e = av.w + adst_i[3]; e = e > 0.f ? e : 0.2f * e; sp[wave][3 * 64 + lane] = __expf(e);
            } else {
                float e = asrc[j] + adst_i[0];
                e = e > 0.f ? e : 0.2f * e;
                sp[wave][lane] = __expf(e);
            }
        }
        asm volatile("s_waitcnt lgkmcnt(0)" ::: "memory");

        int full = cnt & ~3;
        for (int idx = 0; idx < full; idx += 4) {
            int4   j4 = *(const int4*)  &sj[wave][idx];
            float4 p4 = *(const float4*)&sp[wave][head * 64 + idx];
            {
                float2 hv = __half22float2(*(const __half2*)(fb + (size_t)j4.x * 128));
                ssum += p4.x; o0 = fmaf(p4.x, hv.x, o0); o1 = fmaf(p4.x, hv.y, o1);
            }
            {
                float2 hv = __half22float2(*(const __half2*)(fb + (size_t)j4.y * 128));
                ssum += p4.y; o0 = fmaf(p4.y, hv.x, o0); o1 = fmaf(p4.y, hv.y, o1);
            }
            {
                float2 hv = __half22float2(*(const __half2*)(fb + (size_t)j4.z * 128));
                ssum += p4.z; o0 = fmaf(p4.z, hv.x, o0); o1 = fmaf(p4.z, hv.y, o1);
            }
            {
                float2 hv = __half22float2(*(const __half2*)(fb + (size_t)j4.w * 128));
                ssum += p4.w; o0 = fmaf(p4.w, hv.x, o0); o1 = fmaf(p4.w, hv.y, o1);
            }
        }
        for (int idx = full; idx < cnt; ++idx) {
            int j = sj[wave][idx];
            float aa = sp[wave][head * 64 + idx];
            float2 hv = __half22float2(*(const __half2*)(fb + (size_t)j * 128));
            ssum += aa; o0 = fmaf(aa, hv.x, o0); o1 = fmaf(aa, hv.y, o1);
        }
    }

    float inv = 1.f / (ssum + 1e-16f);
    float r0 = o0 * inv + bias[c0];
    float r1 = o1 * inv + bias[c0 + 1];
    r0 = r0 > 0.f ? r0 : expm1f(r0);
    r1 = r1 > 0.f ? r1 : expm1f(r1);
    if constexpr (sizeof(TO) == 2) {
        *(__half2*)((__half*)out + (size_t)node * 128 + c0) = __floats2half2_rn(r0, r1);
    } else {
        *(float2*)((float*)out + (size_t)node * 128 + c0) = make_float2(r0, r1);
    }
}

// ---------------- launch ----------------

extern "C" void kernel_launch(void* const* d_in, const int* in_sizes, int n_in,
                              void* d_out, int out_size, void* d_ws, size_t ws_size,
                              hipStream_t stream)
{
    const float* x    = (const float*)d_in[0];
    const int*   a    = (const int*)  d_in[1];
    const float* W1   = (const float*)d_in[2];
    const float* as1w = (const float*)d_in[3];
    const float* ad1w = (const float*)d_in[4];
    const float* b1   = (const float*)d_in[5];
    const float* W2   = (const float*)d_in[6];
    const float* as2w = (const float*)d_in[7];
    const float* ad2w = (const float*)d_in[8];
    const float* b2   = (const float*)d_in[9];

    const int N = in_sizes[0] / 128;
    const int E = in_sizes[1] / 2;
    const int* srcA = a;
    const int* dstA = a + E;
    const int NBUCK = (N + 127) >> 7;

    char* ws = (char*)d_ws;
    size_t o = 0;
    auto alloc = [&](size_t bytes) -> void* {
        void* p = ws + o;
        o += (bytes + 255) & ~(size_t)255;
        return p;
    };
    __half* hbuf  = (__half*)alloc((size_t)N * 128 * 2);  // fp16 gather payload
    __half* hact  = (__half*)alloc((size_t)N * 128 * 2);  // elu(gat1) fp16, GEMM2 input
    float*  as1   = (float*) alloc((size_t)N * 4 * 4);
    float*  ad1   = (float*) alloc((size_t)N * 4 * 4);
    float*  as2   = (float*) alloc((size_t)N * 4);
    float*  ad2   = (float*) alloc((size_t)N * 4);
    int*    off   = (int*)   alloc((size_t)(N + 1) * 4);
    int*    esrc  = (int*)   alloc((size_t)E * 4);
    int*    tmp   = (int*)   alloc((size_t)E * 4);
    int*    bcnt  = (int*)   alloc(1024 * 4);
    int*    bbase = (int*)   alloc(1025 * 4);
    int*    bcur  = (int*)   alloc(1024 * 4);

    // CSR build (rebuilt each launch; ws is re-poisoned)
    hipMemsetAsync(bcnt, 0, (size_t)NBUCK * 4, stream);
    k_hist<<<256, 256, 0, stream>>>(dstA, bcnt, E, NBUCK);
    k_bscan<<<1, 1024, 0, stream>>>(bcnt, bbase, bcur, off, NBUCK, N, E);
    k_binscatter<<<(E + 8191) / 8192, 256, 0, stream>>>(srcA, dstA, bcur, tmp, E, NBUCK);
    k_bsort<<<NBUCK, 256, 0, stream>>>(tmp, bbase, off, esrc, N);

    // layer 1 (MFMA GEMM + fused attdot, fp16 Y)
    k_gemm_mfma<4, float><<<512, 256, 0, stream>>>(x, W1, as1w, ad1w, hbuf, as1, ad1, N);
    k_agg<4, __half><<<(N + 3) / 4, 256, 0, stream>>>(hbuf, as1, ad1, off, esrc, b1, hact, N);

    // layer 2
    k_gemm_mfma<1, __half><<<512, 256, 0, stream>>>(hact, W2, as2w, ad2w, hbuf, as2, ad2, N);
    k_agg<1, float><<<(N + 3) / 4, 256, 0, stream>>>(hbuf, as2, ad2, off, esrc, b2, (float*)d_out, N);
}